// Round 3
// baseline (401.356 us; speedup 1.0000x reference)
//
#include <hip/hip_runtime.h>
#include <hip/hip_bf16.h>

#define NB 2
#define NL 2048
#define ND 2048
#define NH 16
#define NDK 128
#define SCALE 0.08838834764831845f

#define AS1 __attribute__((address_space(1)))
#define AS3 __attribute__((address_space(3)))

typedef __attribute__((ext_vector_type(8))) __bf16 bf16x8;
typedef __attribute__((ext_vector_type(4))) float f32x4;

__device__ __forceinline__ unsigned short f2bf(float f) {
    union { float f; unsigned u; } v; v.f = f;
    return (unsigned short)((v.u + 0x7fffu + ((v.u >> 16) & 1u)) >> 16);
}
__device__ __forceinline__ float bf2f(unsigned short h) {
    union { unsigned u; float f; } v; v.u = ((unsigned)h) << 16;
    return v.f;
}

// ============ fp32 -> bf16 flat convert (x) =============================================
__global__ __launch_bounds__(256)
void convert_bf16_kernel(const float* __restrict__ in, unsigned short* __restrict__ outp)
{
    int i = blockIdx.x * 256 + threadIdx.x;
    const float4 a = ((const float4*)in)[2 * i];
    const float4 b = ((const float4*)in)[2 * i + 1];
    unsigned short t[8] = { f2bf(a.x), f2bf(a.y), f2bf(a.z), f2bf(a.w),
                            f2bf(b.x), f2bf(b.y), f2bf(b.z), f2bf(b.w) };
    ((uint4*)outp)[i] = *(uint4*)t;
}

// ============ fp32 (R x C) -> bf16 transposed (C x R), 64x64 LDS tiles ==================
__global__ __launch_bounds__(256)
void transpose_convert_kernel(const float* __restrict__ in, unsigned short* __restrict__ outp,
                              int R, int C)
{
    __shared__ float T[64][65];
    const int tr0 = blockIdx.y * 64;
    const int tc0 = blockIdx.x * 64;
    const int t = threadIdx.x;
    const int r = t >> 2;
    const int q = t & 3;
    const float* src = in + (size_t)(tr0 + r) * C + tc0 + q * 16;
    #pragma unroll
    for (int i = 0; i < 4; i++) {
        float4 f = *(const float4*)(src + 4 * i);
        T[r][q * 16 + 4 * i + 0] = f.x;
        T[r][q * 16 + 4 * i + 1] = f.y;
        T[r][q * 16 + 4 * i + 2] = f.z;
        T[r][q * 16 + 4 * i + 3] = f.w;
    }
    __syncthreads();
    unsigned short tmp[16];
    #pragma unroll
    for (int i = 0; i < 16; i++) tmp[i] = f2bf(T[q * 16 + i][r]);
    unsigned short* dst = outp + (size_t)(tc0 + r) * R + tr0 + q * 16;
    *(uint4*)dst       = *(uint4*)&tmp[0];
    *(uint4*)(dst + 8) = *(uint4*)&tmp[8];
}

// ============ per-head V transpose: v fp32 (BH, L, DK) -> Vt bf16 (BH, DK, L) ===========
__global__ __launch_bounds__(256)
void transpose_v_kernel(const float* __restrict__ v, unsigned short* __restrict__ vt)
{
    __shared__ float T[64][65];
    const int bh = blockIdx.z;
    const int l0 = blockIdx.y * 64;
    const int d0 = blockIdx.x * 64;
    const int t = threadIdx.x;
    const int r = t >> 2;
    const int q = t & 3;
    const float* src = v + (size_t)bh * NL * NDK + (size_t)(l0 + r) * NDK + d0 + q * 16;
    #pragma unroll
    for (int i = 0; i < 4; i++) {
        float4 f = *(const float4*)(src + 4 * i);
        T[r][q * 16 + 4 * i + 0] = f.x;
        T[r][q * 16 + 4 * i + 1] = f.y;
        T[r][q * 16 + 4 * i + 2] = f.z;
        T[r][q * 16 + 4 * i + 3] = f.w;
    }
    __syncthreads();
    unsigned short tmp[16];
    #pragma unroll
    for (int i = 0; i < 16; i++) tmp[i] = f2bf(T[q * 16 + i][r]);
    unsigned short* dst = vt + (size_t)bh * NDK * NL + (size_t)(d0 + r) * NL + l0 + q * 16;
    *(uint4*)dst       = *(uint4*)&tmp[0];
    *(uint4*)(dst + 8) = *(uint4*)&tmp[8];
}

// ============ pipelined bf16 GEMM (validated round 10): C = A @ Bt^T ====================
template<int EPI>
__global__ __launch_bounds__(256)
void gemm_bf16(const unsigned short* __restrict__ A, const unsigned short* __restrict__ Bt,
               float* __restrict__ y_dst,
               unsigned short* __restrict__ q_raw,
               float* __restrict__ k_dst, float* __restrict__ v_dst,
               int K, int NT)
{
    __shared__ __align__(16) unsigned short As[3][128][32];
    __shared__ __align__(16) unsigned short Bs[3][128][32];

    const int tid = threadIdx.x;
    const int lane = tid & 63;
    const int l16 = lane & 15, g = lane >> 4;
    const int w = tid >> 6;
    const int wr = w >> 1, wc = w & 1;

    const int cpn = NT >> 3;
    const int bid = blockIdx.x;
    const int xcd = bid & 7, local = bid >> 3;
    const int bx = xcd * cpn + local % cpn;
    const int by = local / cpn;
    const int m0 = by * 128, n0 = bx * 128;

    const int rowl = (w << 4) + (lane >> 2);
    const int swl = (rowl >> 1) & 3;
    const int kofl = ((lane & 3) ^ swl) << 3;
    const unsigned short* gA = A + (size_t)(m0 + rowl) * K + kofl;
    const unsigned short* gB = Bt + (size_t)(n0 + rowl) * K + kofl;
    const int ldsoff = (w << 10) + (lane << 4);

    f32x4 acc[4][4] = {};
    const int NTILES = K >> 5;

    auto STAGE = [&](int t, int buf) {
        const int k0 = t << 5;
        char* baseA = (char*)&As[buf][0][0] + ldsoff;
        char* baseB = (char*)&Bs[buf][0][0] + ldsoff;
        #pragma unroll
        for (int i = 0; i < 2; i++) {
            __builtin_amdgcn_global_load_lds((const AS1 void*)(gA + (size_t)i * 64 * K + k0),
                                             (AS3 void*)(baseA + i * 4096), 16, 0, 0);
            __builtin_amdgcn_global_load_lds((const AS1 void*)(gB + (size_t)i * 64 * K + k0),
                                             (AS3 void*)(baseB + i * 4096), 16, 0, 0);
        }
    };

    const int rsw = (l16 >> 1) & 3;

    STAGE(0, 0); STAGE(1, 1);

    int bufC = 0;
    for (int t = 0; t < NTILES; t++) {
        const int bufS = (bufC == 0) ? 2 : bufC - 1;
        if (t + 2 < NTILES) STAGE(t + 2, bufS);
        if (t + 2 < NTILES)      asm volatile("s_waitcnt vmcnt(8)" ::: "memory");
        else if (t + 1 < NTILES) asm volatile("s_waitcnt vmcnt(4)" ::: "memory");
        else                     asm volatile("s_waitcnt vmcnt(0)" ::: "memory");
        __builtin_amdgcn_s_barrier();
        __builtin_amdgcn_sched_barrier(0);

        const char* pa = (const char*)&As[bufC][0][0];
        const char* pb = (const char*)&Bs[bufC][0][0];
        bf16x8 af[4], bfr[4];
        #pragma unroll
        for (int r = 0; r < 4; r++) {
            int row = wr * 64 + r * 16 + l16;
            af[r] = *(const bf16x8*)(pa + row * 64 + ((g ^ rsw) << 4));
        }
        #pragma unroll
        for (int c = 0; c < 4; c++) {
            int row = wc * 64 + c * 16 + l16;
            bfr[c] = *(const bf16x8*)(pb + row * 64 + ((g ^ rsw) << 4));
        }
        #pragma unroll
        for (int r = 0; r < 4; r++)
            #pragma unroll
            for (int c = 0; c < 4; c++)
                acc[r][c] = __builtin_amdgcn_mfma_f32_16x16x32_bf16(af[r], bfr[c], acc[r][c], 0, 0, 0);

        __builtin_amdgcn_s_barrier();
        __builtin_amdgcn_sched_barrier(0);
        bufC = (bufC == 2) ? 0 : bufC + 1;
    }

    if constexpr (EPI == 0) {
        const int m3 = bx >> 4, h = bx & 15;
        #pragma unroll
        for (int r = 0; r < 4; r++) {
            int mrow = m0 + wr * 64 + r * 16 + g * 4;
            int b = mrow >> 11, l = mrow & 2047;
            size_t rb = ((size_t)(b * NH + h) * NL + l) * NDK;
            #pragma unroll
            for (int c = 0; c < 4; c++) {
                int dk = wc * 64 + c * 16 + l16;
                #pragma unroll
                for (int i = 0; i < 4; i++) {
                    float val = acc[r][c][i];
                    size_t off = rb + (size_t)i * NDK + dk;
                    if (m3 == 0) q_raw[off] = f2bf(val);
                    else if (m3 == 1) k_dst[off] = val;
                    else v_dst[off] = val;
                }
            }
        }
    } else {
        #pragma unroll
        for (int r = 0; r < 4; r++) {
            int mrow = m0 + wr * 64 + r * 16 + g * 4;
            #pragma unroll
            for (int c = 0; c < 4; c++) {
                int ncol = n0 + wc * 64 + c * 16 + l16;
                #pragma unroll
                for (int i = 0; i < 4; i++)
                    y_dst[(size_t)(mrow + i) * ND + ncol] = acc[r][c][i];
            }
        }
    }
}

// ============ RoPE on k only: fp32 in-place (final) + bf16 copy =========================
__global__ __launch_bounds__(256)
void rope_k_kernel(float* __restrict__ kp, unsigned short* __restrict__ k_bf,
                   const float* __restrict__ ct, const float* __restrict__ st)
{
    int idx = blockIdx.x * 256 + threadIdx.x;
    int d = idx & 63;
    int rr = idx >> 6;
    size_t ro = (size_t)rr * NDK;
    int l = rr & (NL - 1);
    float c = ct[l * 64 + d], s = st[l * 64 + d];
    float t1 = kp[ro + d], t2 = kp[ro + d + 64];
    float o1 = t1 * c - t2 * s, o2 = t1 * s + t2 * c;
    kp[ro + d] = o1; kp[ro + d + 64] = o2;
    k_bf[ro + d]      = f2bf(o1);
    k_bf[ro + d + 64] = f2bf(o2);
}

// ============ MFMA flash attention: KVBLK=128, single fused softmax per tile ============
// Round-10 structure scaled to 128-wide KV tiles: Ks[128][128] (32K), Vts[128 d][128 kv]
// (32K), Ps[4][16][128] (16K) = 80 KiB -> 2 blocks/CU. T14 prefetch = 16 named uint4
// (no arrays -- spill rule). Per tile: 32 QK MFMA, one softmax pass (8 chunks, one
// max-reduce + rescale), 32 PV MFMA. Halves barrier count and rescale VALU vs KVBLK=64.
// All XOR swizzles are (row&7)<<4 on byte-chunks; they permute within 128-byte halves,
// identical scheme on write and read sides (rule #21 both-sides).
__global__ __launch_bounds__(256)
void attn_kernel(const unsigned short* __restrict__ q,
                 const unsigned short* __restrict__ k,
                 const unsigned short* __restrict__ vt,
                 unsigned short* __restrict__ attn_out,
                 const float* __restrict__ ct, const float* __restrict__ st)
{
    __shared__ __align__(16) unsigned short Ks[128][128];
    __shared__ __align__(16) unsigned short Vts[128][128];
    __shared__ __align__(16) unsigned short Ps[4][16][128];

    char* const ksb = (char*)&Ks[0][0];
    char* const vsb = (char*)&Vts[0][0];
    char* const psb = (char*)&Ps[0][0][0];

    const int tid = threadIdx.x, lane = tid & 63, w = tid >> 6;
    const int l16 = lane & 15, g = lane >> 4;
    const int bh = blockIdx.x;
    const int b = bh >> 4, h = bh & 15;
    const size_t base = (size_t)bh * NL * NDK;

    // K staging: 2 threads per kv-row (128 rows x 128 d), each 64 shorts (8 uint4)
    const int krow = tid >> 1;
    const int kq = tid & 1;
    const int kwb = krow * 256 + kq * 128;
    const int kwx = (krow & 7) << 4;
    // V staging: 2 threads per d-row (128 rows x 128 kv), each 64 shorts (8 uint4)
    const int vrow = tid >> 1;
    const int vh = tid & 1;
    const int vwb = vrow * 256 + vh * 128;
    const int vwx = (vrow & 7) << 4;

    const int rdx = (l16 & 7) << 4;

    const unsigned short* const kbase = k + base + (size_t)krow * NDK + kq * 64;
    const unsigned short* const vbase = vt + base + (size_t)vrow * NL + vh * 64;

    for (int half = 0; half < 2; half++) {
        const int jq = half ? (int)blockIdx.y : 31 - (int)blockIdx.y;
        const int qb = jq * 64;

        // ---- Q load with fused RoPE ----
        bf16x8 aq[4];
        {
            const int l = qb + w * 16 + l16;
            const unsigned short* src = q + base + (size_t)l * NDK + g * 8;
            union { bf16x8 v; unsigned short s[8]; } raw[4], outv[4];
            #pragma unroll
            for (int ks2 = 0; ks2 < 4; ks2++) raw[ks2].v = *(const bf16x8*)(src + ks2 * 32);
            const float* cb = ct + (size_t)l * 64 + g * 8;
            const float* sb = st + (size_t)l * 64 + g * 8;
            float cv[2][8], sv2[2][8];
            #pragma unroll
            for (int hh = 0; hh < 2; hh++) {
                float4 c0 = *(const float4*)(cb + 32 * hh);
                float4 c1 = *(const float4*)(cb + 32 * hh + 4);
                float4 s0 = *(const float4*)(sb + 32 * hh);
                float4 s1 = *(const float4*)(sb + 32 * hh + 4);
                cv[hh][0]=c0.x; cv[hh][1]=c0.y; cv[hh][2]=c0.z; cv[hh][3]=c0.w;
                cv[hh][4]=c1.x; cv[hh][5]=c1.y; cv[hh][6]=c1.z; cv[hh][7]=c1.w;
                sv2[hh][0]=s0.x; sv2[hh][1]=s0.y; sv2[hh][2]=s0.z; sv2[hh][3]=s0.w;
                sv2[hh][4]=s1.x; sv2[hh][5]=s1.y; sv2[hh][6]=s1.z; sv2[hh][7]=s1.w;
            }
            #pragma unroll
            for (int hh = 0; hh < 2; hh++)
                #pragma unroll
                for (int j = 0; j < 8; j++) {
                    float t1 = bf2f(raw[hh].s[j]), t2 = bf2f(raw[hh + 2].s[j]);
                    float c = cv[hh][j], s = sv2[hh][j];
                    outv[hh].s[j]     = f2bf(t1 * c - t2 * s);
                    outv[hh + 2].s[j] = f2bf(t1 * s + t2 * c);
                }
            #pragma unroll
            for (int ks2 = 0; ks2 < 4; ks2++) aq[ks2] = outv[ks2].v;
        }

        f32x4 o[8] = {};
        float m_r[4], lv[4];
        #pragma unroll
        for (int i = 0; i < 4; i++) { m_r[i] = -1e30f; lv[i] = 0.f; }

        // ---- T14 prologue: tile 0 into 16 named registers ----
        uint4 pk0, pk1, pk2, pk3, pk4, pk5, pk6, pk7;
        uint4 pv0, pv1, pv2, pv3, pv4, pv5, pv6, pv7;
        {
            const unsigned short* ks = kbase;            // kv0 = 0
            pk0 = *(const uint4*)(ks);      pk1 = *(const uint4*)(ks + 8);
            pk2 = *(const uint4*)(ks + 16); pk3 = *(const uint4*)(ks + 24);
            pk4 = *(const uint4*)(ks + 32); pk5 = *(const uint4*)(ks + 40);
            pk6 = *(const uint4*)(ks + 48); pk7 = *(const uint4*)(ks + 56);
            const unsigned short* vs = vbase;
            pv0 = *(const uint4*)(vs);      pv1 = *(const uint4*)(vs + 8);
            pv2 = *(const uint4*)(vs + 16); pv3 = *(const uint4*)(vs + 24);
            pv4 = *(const uint4*)(vs + 32); pv5 = *(const uint4*)(vs + 40);
            pv6 = *(const uint4*)(vs + 48); pv7 = *(const uint4*)(vs + 56);
        }

        for (int kv0 = 0; kv0 <= qb; kv0 += 128) {
            __syncthreads();                 // prior reads done; implicit vmcnt(0) lands prefetch
            *(uint4*)(ksb + ((kwb      ) ^ kwx)) = pk0;
            *(uint4*)(ksb + ((kwb +  16) ^ kwx)) = pk1;
            *(uint4*)(ksb + ((kwb +  32) ^ kwx)) = pk2;
            *(uint4*)(ksb + ((kwb +  48) ^ kwx)) = pk3;
            *(uint4*)(ksb + ((kwb +  64) ^ kwx)) = pk4;
            *(uint4*)(ksb + ((kwb +  80) ^ kwx)) = pk5;
            *(uint4*)(ksb + ((kwb +  96) ^ kwx)) = pk6;
            *(uint4*)(ksb + ((kwb + 112) ^ kwx)) = pk7;
            *(uint4*)(vsb + ((vwb      ) ^ vwx)) = pv0;
            *(uint4*)(vsb + ((vwb +  16) ^ vwx)) = pv1;
            *(uint4*)(vsb + ((vwb +  32) ^ vwx)) = pv2;
            *(uint4*)(vsb + ((vwb +  48) ^ vwx)) = pv3;
            *(uint4*)(vsb + ((vwb +  64) ^ vwx)) = pv4;
            *(uint4*)(vsb + ((vwb +  80) ^ vwx)) = pv5;
            *(uint4*)(vsb + ((vwb +  96) ^ vwx)) = pv6;
            *(uint4*)(vsb + ((vwb + 112) ^ vwx)) = pv7;
            __syncthreads();                 // LDS tile visible to all waves

            if (kv0 + 128 <= qb) {           // T14: issue next tile now (inline, named)
                const unsigned short* ks = kbase + (size_t)(kv0 + 128) * NDK;
                pk0 = *(const uint4*)(ks);      pk1 = *(const uint4*)(ks + 8);
                pk2 = *(const uint4*)(ks + 16); pk3 = *(const uint4*)(ks + 24);
                pk4 = *(const uint4*)(ks + 32); pk5 = *(const uint4*)(ks + 40);
                pk6 = *(const uint4*)(ks + 48); pk7 = *(const uint4*)(ks + 56);
                const unsigned short* vs = vbase + kv0 + 128;
                pv0 = *(const uint4*)(vs);      pv1 = *(const uint4*)(vs + 8);
                pv2 = *(const uint4*)(vs + 16); pv3 = *(const uint4*)(vs + 24);
                pv4 = *(const uint4*)(vs + 32); pv5 = *(const uint4*)(vs + 40);
                pv6 = *(const uint4*)(vs + 48); pv7 = *(const uint4*)(vs + 56);
                __builtin_amdgcn_sched_barrier(0);   // pin issue point before compute
            }

            // ---- QK^T: 32 MFMAs over 128 kv cols ----
            f32x4 sv[8];
            __builtin_amdgcn_s_setprio(1);
            #pragma unroll
            for (int cf = 0; cf < 8; cf++) {
                const int krb = (cf * 16 + l16) * 256 + g * 16;
                f32x4 a = {};
                #pragma unroll
                for (int ks2 = 0; ks2 < 4; ks2++) {
                    bf16x8 kf = *(const bf16x8*)(ksb + ((krb + 64 * ks2) ^ rdx));
                    a = __builtin_amdgcn_mfma_f32_16x16x32_bf16(aq[ks2], kf, a, 0, 0, 0);
                }
                sv[cf] = a;
            }
            __builtin_amdgcn_s_setprio(0);

            // ---- online softmax: one pass over 8 chunks (deferred l-sum) ----
            const int kvl = kv0 + l16;
            const int rowb = qb + w * 16 + g * 4;
            #pragma unroll
            for (int i = 0; i < 4; i++) {
                const int row = rowb + i;
                float s[8];
                #pragma unroll
                for (int cf = 0; cf < 8; cf++) {
                    float x = sv[cf][i] * SCALE;
                    if (kvl + 16 * cf > row) x = -1e30f;
                    s[cf] = x;
                }
                float mx = fmaxf(fmaxf(fmaxf(s[0], s[1]), fmaxf(s[2], s[3])),
                                 fmaxf(fmaxf(s[4], s[5]), fmaxf(s[6], s[7])));
                mx = fmaxf(mx, __shfl_xor(mx, 1));
                mx = fmaxf(mx, __shfl_xor(mx, 2));
                mx = fmaxf(mx, __shfl_xor(mx, 4));
                mx = fmaxf(mx, __shfl_xor(mx, 8));
                float mnew = fmaxf(m_r[i], mx);
                float fac = __expf(m_r[i] - mnew);
                float p[8], psum = 0.f;
                #pragma unroll
                for (int cf = 0; cf < 8; cf++) { p[cf] = __expf(s[cf] - mnew); psum += p[cf]; }
                lv[i] = lv[i] * fac + psum;
                m_r[i] = mnew;
                #pragma unroll
                for (int c8 = 0; c8 < 8; c8++) o[c8][i] *= fac;
                const int pr = g * 4 + i;
                char* pw = psb + w * 4096 + pr * 256;
                const int px = (pr & 7) << 4;
                const int cb2 = l16 << 1;
                #pragma unroll
                for (int cf = 0; cf < 8; cf++)
                    *(unsigned short*)(pw + ((cb2 + 32 * cf) ^ px)) = f2bf(p[cf]);
            }
            // wave-local LDS RAW (Ps write -> cross-lane read): drain + pin (rule #18)
            asm volatile("s_waitcnt lgkmcnt(0)" ::: "memory");
            __builtin_amdgcn_sched_barrier(0);

            // ---- PV: 32 MFMAs ----
            bf16x8 pf[4];
            #pragma unroll
            for (int kc = 0; kc < 4; kc++)
                pf[kc] = *(const bf16x8*)(psb + w * 4096 + l16 * 256 + ((kc * 64 + g * 16) ^ rdx));
            __builtin_amdgcn_s_setprio(1);
            #pragma unroll
            for (int c8 = 0; c8 < 8; c8++) {
                const int vrb = (c8 * 16 + l16) * 256 + g * 16;
                #pragma unroll
                for (int kc = 0; kc < 4; kc++) {
                    bf16x8 vf = *(const bf16x8*)(vsb + ((vrb + kc * 64) ^ rdx));
                    o[c8] = __builtin_amdgcn_mfma_f32_16x16x32_bf16(pf[kc], vf, o[c8], 0, 0, 0);
                }
            }
            __builtin_amdgcn_s_setprio(0);
        }

        #pragma unroll
        for (int i = 0; i < 4; i++) {
            float ls = lv[i];
            ls += __shfl_xor(ls, 1);
            ls += __shfl_xor(ls, 2);
            ls += __shfl_xor(ls, 4);
            ls += __shfl_xor(ls, 8);
            float inv = 1.0f / ls;
            int qrow = qb + w * 16 + g * 4 + i;
            size_t rb = ((size_t)(b * NL + qrow)) * ND + h * NDK;
            #pragma unroll
            for (int c8 = 0; c8 < 8; c8++)
                attn_out[rb + c8 * 16 + l16] = f2bf(o[c8][i] * inv);
        }
    }
}

__global__ void ws_signature_kernel(float* y) { if (threadIdx.x == 0) y[0] = 12345.0f; }

extern "C" void kernel_launch(void* const* d_in, const int* in_sizes, int n_in,
                              void* d_out, int out_size, void* d_ws, size_t ws_size,
                              hipStream_t stream)
{
    const float* x     = (const float*)d_in[0];
    const float* w_qkv = (const float*)d_in[1];
    const float* w_o   = (const float*)d_in[2];
    const float* ct    = (const float*)d_in[3];
    const float* st    = (const float*)d_in[4];

    const size_t NTOK = (size_t)NB * NL * ND;
    float* y_out = (float*)d_out;
    float* k_out = y_out + NTOK;
    float* v_out = y_out + 2 * NTOK;

    const size_t need = (6 * NTOK + 4 * (size_t)ND * ND) * sizeof(unsigned short);
    if (ws_size < need) {
        ws_signature_kernel<<<1, 64, 0, stream>>>(y_out);
        return;
    }
    unsigned short* x_bf  = (unsigned short*)d_ws;
    unsigned short* Wt    = x_bf + NTOK;
    unsigned short* Wt_o  = Wt + (size_t)3 * ND * ND;
    unsigned short* q_raw = Wt_o + (size_t)ND * ND;
    unsigned short* q_bf  = q_raw + NTOK;        // unused (kept for layout)
    unsigned short* k_bf  = q_bf + NTOK;
    unsigned short* Vt    = k_bf + NTOK;
    unsigned short* a_bf  = Vt + NTOK;

    convert_bf16_kernel<<<4096, 256, 0, stream>>>(x, x_bf);
    transpose_convert_kernel<<<dim3(96, 32), 256, 0, stream>>>(w_qkv, Wt, ND, 3 * ND);
    transpose_convert_kernel<<<dim3(32, 32), 256, 0, stream>>>(w_o, Wt_o, ND, ND);
    gemm_bf16<0><<<1536, 256, 0, stream>>>(x_bf, Wt, nullptr, q_raw, k_out, v_out, ND, 48);
    rope_k_kernel<<<16384, 256, 0, stream>>>(k_out, k_bf, ct, st);
    transpose_v_kernel<<<dim3(2, 32, 32), 256, 0, stream>>>(v_out, Vt);
    attn_kernel<<<dim3(32, 16), 256, 0, stream>>>(q_raw, k_bf, Vt, a_bf, ct, st);
    gemm_bf16<1><<<512, 256, 0, stream>>>(a_bf, Wt_o, y_out, nullptr, nullptr, nullptr, ND, 16);
}

// Round 4
// 376.258 us; speedup vs baseline: 1.0667x; 1.0667x over previous
//
#include <hip/hip_runtime.h>
#include <hip/hip_bf16.h>

#define NB 2
#define NL 2048
#define ND 2048
#define NH 16
#define NDK 128
#define SCALE 0.08838834764831845f

#define AS1 __attribute__((address_space(1)))
#define AS3 __attribute__((address_space(3)))

typedef __attribute__((ext_vector_type(8))) __bf16 bf16x8;
typedef __attribute__((ext_vector_type(4))) float f32x4;

__device__ __forceinline__ unsigned short f2bf(float f) {
    union { float f; unsigned u; } v; v.f = f;
    return (unsigned short)((v.u + 0x7fffu + ((v.u >> 16) & 1u)) >> 16);
}
__device__ __forceinline__ float bf2f(unsigned short h) {
    union { unsigned u; float f; } v; v.u = ((unsigned)h) << 16;
    return v.f;
}

// ============ fp32 -> bf16 flat convert (x) =============================================
__global__ __launch_bounds__(256)
void convert_bf16_kernel(const float* __restrict__ in, unsigned short* __restrict__ outp)
{
    int i = blockIdx.x * 256 + threadIdx.x;
    const float4 a = ((const float4*)in)[2 * i];
    const float4 b = ((const float4*)in)[2 * i + 1];
    unsigned short t[8] = { f2bf(a.x), f2bf(a.y), f2bf(a.z), f2bf(a.w),
                            f2bf(b.x), f2bf(b.y), f2bf(b.z), f2bf(b.w) };
    ((uint4*)outp)[i] = *(uint4*)t;
}

// ============ fp32 (R x C) -> bf16 transposed (C x R), 64x64 LDS tiles ==================
__global__ __launch_bounds__(256)
void transpose_convert_kernel(const float* __restrict__ in, unsigned short* __restrict__ outp,
                              int R, int C)
{
    __shared__ float T[64][65];
    const int tr0 = blockIdx.y * 64;
    const int tc0 = blockIdx.x * 64;
    const int t = threadIdx.x;
    const int r = t >> 2;
    const int q = t & 3;
    const float* src = in + (size_t)(tr0 + r) * C + tc0 + q * 16;
    #pragma unroll
    for (int i = 0; i < 4; i++) {
        float4 f = *(const float4*)(src + 4 * i);
        T[r][q * 16 + 4 * i + 0] = f.x;
        T[r][q * 16 + 4 * i + 1] = f.y;
        T[r][q * 16 + 4 * i + 2] = f.z;
        T[r][q * 16 + 4 * i + 3] = f.w;
    }
    __syncthreads();
    unsigned short tmp[16];
    #pragma unroll
    for (int i = 0; i < 16; i++) tmp[i] = f2bf(T[q * 16 + i][r]);
    unsigned short* dst = outp + (size_t)(tc0 + r) * R + tr0 + q * 16;
    *(uint4*)dst       = *(uint4*)&tmp[0];
    *(uint4*)(dst + 8) = *(uint4*)&tmp[8];
}

// ============ per-head V transpose: v fp32 (BH, L, DK) -> Vt bf16 (BH, DK, L) ===========
__global__ __launch_bounds__(256)
void transpose_v_kernel(const float* __restrict__ v, unsigned short* __restrict__ vt)
{
    __shared__ float T[64][65];
    const int bh = blockIdx.z;
    const int l0 = blockIdx.y * 64;
    const int d0 = blockIdx.x * 64;
    const int t = threadIdx.x;
    const int r = t >> 2;
    const int q = t & 3;
    const float* src = v + (size_t)bh * NL * NDK + (size_t)(l0 + r) * NDK + d0 + q * 16;
    #pragma unroll
    for (int i = 0; i < 4; i++) {
        float4 f = *(const float4*)(src + 4 * i);
        T[r][q * 16 + 4 * i + 0] = f.x;
        T[r][q * 16 + 4 * i + 1] = f.y;
        T[r][q * 16 + 4 * i + 2] = f.z;
        T[r][q * 16 + 4 * i + 3] = f.w;
    }
    __syncthreads();
    unsigned short tmp[16];
    #pragma unroll
    for (int i = 0; i < 16; i++) tmp[i] = f2bf(T[q * 16 + i][r]);
    unsigned short* dst = vt + (size_t)bh * NDK * NL + (size_t)(d0 + r) * NL + l0 + q * 16;
    *(uint4*)dst       = *(uint4*)&tmp[0];
    *(uint4*)(dst + 8) = *(uint4*)&tmp[8];
}

// ============ pipelined bf16 GEMM (validated round 10): C = A @ Bt^T ====================
template<int EPI>
__global__ __launch_bounds__(256)
void gemm_bf16(const unsigned short* __restrict__ A, const unsigned short* __restrict__ Bt,
               float* __restrict__ y_dst,
               unsigned short* __restrict__ q_raw,
               float* __restrict__ k_dst, float* __restrict__ v_dst,
               int K, int NT)
{
    __shared__ __align__(16) unsigned short As[3][128][32];
    __shared__ __align__(16) unsigned short Bs[3][128][32];

    const int tid = threadIdx.x;
    const int lane = tid & 63;
    const int l16 = lane & 15, g = lane >> 4;
    const int w = tid >> 6;
    const int wr = w >> 1, wc = w & 1;

    const int cpn = NT >> 3;
    const int bid = blockIdx.x;
    const int xcd = bid & 7, local = bid >> 3;
    const int bx = xcd * cpn + local % cpn;
    const int by = local / cpn;
    const int m0 = by * 128, n0 = bx * 128;

    const int rowl = (w << 4) + (lane >> 2);
    const int swl = (rowl >> 1) & 3;
    const int kofl = ((lane & 3) ^ swl) << 3;
    const unsigned short* gA = A + (size_t)(m0 + rowl) * K + kofl;
    const unsigned short* gB = Bt + (size_t)(n0 + rowl) * K + kofl;
    const int ldsoff = (w << 10) + (lane << 4);

    f32x4 acc[4][4] = {};
    const int NTILES = K >> 5;

    auto STAGE = [&](int t, int buf) {
        const int k0 = t << 5;
        char* baseA = (char*)&As[buf][0][0] + ldsoff;
        char* baseB = (char*)&Bs[buf][0][0] + ldsoff;
        #pragma unroll
        for (int i = 0; i < 2; i++) {
            __builtin_amdgcn_global_load_lds((const AS1 void*)(gA + (size_t)i * 64 * K + k0),
                                             (AS3 void*)(baseA + i * 4096), 16, 0, 0);
            __builtin_amdgcn_global_load_lds((const AS1 void*)(gB + (size_t)i * 64 * K + k0),
                                             (AS3 void*)(baseB + i * 4096), 16, 0, 0);
        }
    };

    const int rsw = (l16 >> 1) & 3;

    STAGE(0, 0); STAGE(1, 1);

    int bufC = 0;
    for (int t = 0; t < NTILES; t++) {
        const int bufS = (bufC == 0) ? 2 : bufC - 1;
        if (t + 2 < NTILES) STAGE(t + 2, bufS);
        if (t + 2 < NTILES)      asm volatile("s_waitcnt vmcnt(8)" ::: "memory");
        else if (t + 1 < NTILES) asm volatile("s_waitcnt vmcnt(4)" ::: "memory");
        else                     asm volatile("s_waitcnt vmcnt(0)" ::: "memory");
        __builtin_amdgcn_s_barrier();
        __builtin_amdgcn_sched_barrier(0);

        const char* pa = (const char*)&As[bufC][0][0];
        const char* pb = (const char*)&Bs[bufC][0][0];
        bf16x8 af[4], bfr[4];
        #pragma unroll
        for (int r = 0; r < 4; r++) {
            int row = wr * 64 + r * 16 + l16;
            af[r] = *(const bf16x8*)(pa + row * 64 + ((g ^ rsw) << 4));
        }
        #pragma unroll
        for (int c = 0; c < 4; c++) {
            int row = wc * 64 + c * 16 + l16;
            bfr[c] = *(const bf16x8*)(pb + row * 64 + ((g ^ rsw) << 4));
        }
        #pragma unroll
        for (int r = 0; r < 4; r++)
            #pragma unroll
            for (int c = 0; c < 4; c++)
                acc[r][c] = __builtin_amdgcn_mfma_f32_16x16x32_bf16(af[r], bfr[c], acc[r][c], 0, 0, 0);

        __builtin_amdgcn_s_barrier();
        __builtin_amdgcn_sched_barrier(0);
        bufC = (bufC == 2) ? 0 : bufC + 1;
    }

    if constexpr (EPI == 0) {
        const int m3 = bx >> 4, h = bx & 15;
        #pragma unroll
        for (int r = 0; r < 4; r++) {
            int mrow = m0 + wr * 64 + r * 16 + g * 4;
            int b = mrow >> 11, l = mrow & 2047;
            size_t rb = ((size_t)(b * NH + h) * NL + l) * NDK;
            #pragma unroll
            for (int c = 0; c < 4; c++) {
                int dk = wc * 64 + c * 16 + l16;
                #pragma unroll
                for (int i = 0; i < 4; i++) {
                    float val = acc[r][c][i];
                    size_t off = rb + (size_t)i * NDK + dk;
                    if (m3 == 0) q_raw[off] = f2bf(val);
                    else if (m3 == 1) k_dst[off] = val;
                    else v_dst[off] = val;
                }
            }
        }
    } else {
        #pragma unroll
        for (int r = 0; r < 4; r++) {
            int mrow = m0 + wr * 64 + r * 16 + g * 4;
            #pragma unroll
            for (int c = 0; c < 4; c++) {
                int ncol = n0 + wc * 64 + c * 16 + l16;
                #pragma unroll
                for (int i = 0; i < 4; i++)
                    y_dst[(size_t)(mrow + i) * ND + ncol] = acc[r][c][i];
            }
        }
    }
}

// ============ RoPE on k only: fp32 in-place (final) + bf16 copy, float4-vectorized ======
// One thread per 4 d-elements (16 threads/row). Identical traffic to scalar version but
// 16B loads/stores (fp32) and 8B stores (bf16) -- G13.
__global__ __launch_bounds__(256)
void rope_k_kernel(float* __restrict__ kp, unsigned short* __restrict__ k_bf,
                   const float* __restrict__ ct, const float* __restrict__ st)
{
    int idx = blockIdx.x * 256 + threadIdx.x;
    int d = (idx & 15) << 2;
    int rr = idx >> 4;
    size_t ro = (size_t)rr * NDK;
    int l = rr & (NL - 1);
    float4 c  = *(const float4*)(ct + l * 64 + d);
    float4 s  = *(const float4*)(st + l * 64 + d);
    float4 t1 = *(const float4*)(kp + ro + d);
    float4 t2 = *(const float4*)(kp + ro + d + 64);
    float4 o1, o2;
    o1.x = t1.x * c.x - t2.x * s.x;  o2.x = t1.x * s.x + t2.x * c.x;
    o1.y = t1.y * c.y - t2.y * s.y;  o2.y = t1.y * s.y + t2.y * c.y;
    o1.z = t1.z * c.z - t2.z * s.z;  o2.z = t1.z * s.z + t2.z * c.z;
    o1.w = t1.w * c.w - t2.w * s.w;  o2.w = t1.w * s.w + t2.w * c.w;
    *(float4*)(kp + ro + d)      = o1;
    *(float4*)(kp + ro + d + 64) = o2;
    unsigned short u1[4] = { f2bf(o1.x), f2bf(o1.y), f2bf(o1.z), f2bf(o1.w) };
    unsigned short u2[4] = { f2bf(o2.x), f2bf(o2.y), f2bf(o2.z), f2bf(o2.w) };
    *(uint2*)(k_bf + ro + d)      = *(uint2*)u1;
    *(uint2*)(k_bf + ro + d + 64) = *(uint2*)u2;
}

// ============ MFMA flash attention (round-10 structure + named-reg T14 + setprio) =======
// grid (32 bh, 16 by); block does jq = 31-by then by. Wave owns 16 q-rows; fused Q-RoPE.
// KVBLK=64, 40KB LDS, XOR swizzle. T14: next tile's K/V prefetched into NAMED uint4
// registers, consumed by ds_write at next iteration top where __syncthreads' implicit
// vmcnt(0) lands them. NEW this round: T13 defer-max -- skip the O-rescale (32 VALU/lane)
// when the wave-uniform check says the running max grew by <= 8 (P bounded by e^8,
// fp32 accum + bf16 P-store tolerate; guide T13, +5% attn, refcheck'd m239).
__global__ __launch_bounds__(256)
void attn_kernel(const unsigned short* __restrict__ q,
                 const unsigned short* __restrict__ k,
                 const unsigned short* __restrict__ vt,
                 unsigned short* __restrict__ attn_out,
                 const float* __restrict__ ct, const float* __restrict__ st)
{
    __shared__ __align__(16) unsigned short Ks[64][128];
    __shared__ __align__(16) unsigned short Vts[128][64];
    __shared__ __align__(16) unsigned short Ps[4][16][64];

    char* const ksb = (char*)&Ks[0][0];
    char* const vsb = (char*)&Vts[0][0];
    char* const psb = (char*)&Ps[0][0][0];

    const int tid = threadIdx.x, lane = tid & 63, w = tid >> 6;
    const int l16 = lane & 15, g = lane >> 4;
    const int bh = blockIdx.x;
    const int b = bh >> 4, h = bh & 15;
    const size_t base = (size_t)bh * NL * NDK;

    const int krow = tid >> 2;
    const int kq = tid & 3;
    const int kwb = krow * 256 + kq * 64;
    const int kwx = (krow & 7) << 4;
    const int vrow = tid >> 1;
    const int vh = tid & 1;
    const int vwb = vrow * 128 + vh * 64;
    const int vwx = (vrow & 7) << 4;

    const int rdx = (l16 & 7) << 4;

    const unsigned short* const kbase = k + base + (size_t)krow * NDK + kq * 32;
    const unsigned short* const vbase = vt + base + (size_t)vrow * NL + vh * 32;

    for (int half = 0; half < 2; half++) {
        const int jq = half ? (int)blockIdx.y : 31 - (int)blockIdx.y;
        const int qb = jq * 64;

        // ---- Q load with fused RoPE ----
        bf16x8 aq[4];
        {
            const int l = qb + w * 16 + l16;
            const unsigned short* src = q + base + (size_t)l * NDK + g * 8;
            union { bf16x8 v; unsigned short s[8]; } raw[4], outv[4];
            #pragma unroll
            for (int ks2 = 0; ks2 < 4; ks2++) raw[ks2].v = *(const bf16x8*)(src + ks2 * 32);
            const float* cb = ct + (size_t)l * 64 + g * 8;
            const float* sb = st + (size_t)l * 64 + g * 8;
            float cv[2][8], sv2[2][8];
            #pragma unroll
            for (int hh = 0; hh < 2; hh++) {
                float4 c0 = *(const float4*)(cb + 32 * hh);
                float4 c1 = *(const float4*)(cb + 32 * hh + 4);
                float4 s0 = *(const float4*)(sb + 32 * hh);
                float4 s1 = *(const float4*)(sb + 32 * hh + 4);
                cv[hh][0]=c0.x; cv[hh][1]=c0.y; cv[hh][2]=c0.z; cv[hh][3]=c0.w;
                cv[hh][4]=c1.x; cv[hh][5]=c1.y; cv[hh][6]=c1.z; cv[hh][7]=c1.w;
                sv2[hh][0]=s0.x; sv2[hh][1]=s0.y; sv2[hh][2]=s0.z; sv2[hh][3]=s0.w;
                sv2[hh][4]=s1.x; sv2[hh][5]=s1.y; sv2[hh][6]=s1.z; sv2[hh][7]=s1.w;
            }
            #pragma unroll
            for (int hh = 0; hh < 2; hh++)
                #pragma unroll
                for (int j = 0; j < 8; j++) {
                    float t1 = bf2f(raw[hh].s[j]), t2 = bf2f(raw[hh + 2].s[j]);
                    float c = cv[hh][j], s = sv2[hh][j];
                    outv[hh].s[j]     = f2bf(t1 * c - t2 * s);
                    outv[hh + 2].s[j] = f2bf(t1 * s + t2 * c);
                }
            #pragma unroll
            for (int ks2 = 0; ks2 < 4; ks2++) aq[ks2] = outv[ks2].v;
        }

        f32x4 o[8] = {};
        float m_r[4], lv[4];
        #pragma unroll
        for (int i = 0; i < 4; i++) { m_r[i] = -1e30f; lv[i] = 0.f; }

        // ---- T14 prologue: tile 0 into named registers ----
        uint4 pk0, pk1, pk2, pk3, pv0, pv1, pv2, pv3;
        {
            const unsigned short* ks = kbase;           // kv0 = 0
            pk0 = *(const uint4*)(ks);
            pk1 = *(const uint4*)(ks + 8);
            pk2 = *(const uint4*)(ks + 16);
            pk3 = *(const uint4*)(ks + 24);
            const unsigned short* vs = vbase;
            pv0 = *(const uint4*)(vs);
            pv1 = *(const uint4*)(vs + 8);
            pv2 = *(const uint4*)(vs + 16);
            pv3 = *(const uint4*)(vs + 24);
        }

        for (int kv0 = 0; kv0 <= qb; kv0 += 64) {
            __syncthreads();                    // prior reads done; vmcnt(0) lands prefetch
            *(uint4*)(ksb + ((kwb     ) ^ kwx)) = pk0;
            *(uint4*)(ksb + ((kwb + 16) ^ kwx)) = pk1;
            *(uint4*)(ksb + ((kwb + 32) ^ kwx)) = pk2;
            *(uint4*)(ksb + ((kwb + 48) ^ kwx)) = pk3;
            *(uint4*)(vsb + ((vwb     ) ^ vwx)) = pv0;
            *(uint4*)(vsb + ((vwb + 16) ^ vwx)) = pv1;
            *(uint4*)(vsb + ((vwb + 32) ^ vwx)) = pv2;
            *(uint4*)(vsb + ((vwb + 48) ^ vwx)) = pv3;
            __syncthreads();                    // LDS tile visible to all waves

            if (kv0 + 64 <= qb) {               // T14: issue next tile now (inline, named)
                const unsigned short* ks = kbase + (size_t)(kv0 + 64) * NDK;
                pk0 = *(const uint4*)(ks);
                pk1 = *(const uint4*)(ks + 8);
                pk2 = *(const uint4*)(ks + 16);
                pk3 = *(const uint4*)(ks + 24);
                const unsigned short* vs = vbase + kv0 + 64;
                pv0 = *(const uint4*)(vs);
                pv1 = *(const uint4*)(vs + 8);
                pv2 = *(const uint4*)(vs + 16);
                pv3 = *(const uint4*)(vs + 24);
                __builtin_amdgcn_sched_barrier(0);  // pin issue point before compute
            }

            // ---- QK^T: 16 MFMAs ----
            f32x4 sv[4];
            __builtin_amdgcn_s_setprio(1);
            #pragma unroll
            for (int cf = 0; cf < 4; cf++) {
                const int krb = (cf * 16 + l16) * 256 + g * 16;
                f32x4 a = {};
                #pragma unroll
                for (int ks2 = 0; ks2 < 4; ks2++) {
                    bf16x8 kf = *(const bf16x8*)(ksb + ((krb + 64 * ks2) ^ rdx));
                    a = __builtin_amdgcn_mfma_f32_16x16x32_bf16(aq[ks2], kf, a, 0, 0, 0);
                }
                sv[cf] = a;
            }
            __builtin_amdgcn_s_setprio(0);

            // ---- online softmax (deferred l-sum + T13 defer-max) ----
            const int kvl = kv0 + l16;
            const int rowb = qb + w * 16 + g * 4;
            #pragma unroll
            for (int i = 0; i < 4; i++) {
                int row = rowb + i;
                float s0 = sv[0][i] * SCALE;
                float s1 = sv[1][i] * SCALE;
                float s2 = sv[2][i] * SCALE;
                float s3 = sv[3][i] * SCALE;
                if (kvl      > row) s0 = -1e30f;
                if (kvl + 16 > row) s1 = -1e30f;
                if (kvl + 32 > row) s2 = -1e30f;
                if (kvl + 48 > row) s3 = -1e30f;
                float mx = fmaxf(fmaxf(s0, s1), fmaxf(s2, s3));
                mx = fmaxf(mx, __shfl_xor(mx, 1));
                mx = fmaxf(mx, __shfl_xor(mx, 2));
                mx = fmaxf(mx, __shfl_xor(mx, 4));
                mx = fmaxf(mx, __shfl_xor(mx, 8));
                // T13: wave-uniform skip of the rescale when max growth <= 8
                if (!__all(mx <= m_r[i] + 8.0f)) {
                    float mnew = fmaxf(m_r[i], mx);
                    float fac = __expf(m_r[i] - mnew);
                    lv[i] *= fac;
                    #pragma unroll
                    for (int c8 = 0; c8 < 8; c8++) o[c8][i] *= fac;
                    m_r[i] = mnew;
                }
                float p0 = __expf(s0 - m_r[i]);
                float p1 = __expf(s1 - m_r[i]);
                float p2 = __expf(s2 - m_r[i]);
                float p3 = __expf(s3 - m_r[i]);
                lv[i] += (p0 + p1) + (p2 + p3);
                const int pr = g * 4 + i;
                char* pw = psb + w * 2048 + pr * 128;
                const int px = (pr & 7) << 4;
                const int cb2 = l16 << 1;
                *(unsigned short*)(pw + ((cb2)      ^ px)) = f2bf(p0);
                *(unsigned short*)(pw + ((cb2 + 32) ^ px)) = f2bf(p1);
                *(unsigned short*)(pw + ((cb2 + 64) ^ px)) = f2bf(p2);
                *(unsigned short*)(pw + ((cb2 + 96) ^ px)) = f2bf(p3);
            }
            // wave-local LDS RAW (Ps write -> cross-lane read): drain + pin (rule #18)
            asm volatile("s_waitcnt lgkmcnt(0)" ::: "memory");
            __builtin_amdgcn_sched_barrier(0);

            // ---- PV: 16 MFMAs ----
            bf16x8 pf[2];
            #pragma unroll
            for (int kc = 0; kc < 2; kc++)
                pf[kc] = *(const bf16x8*)(psb + w * 2048 + l16 * 128 + ((kc * 64 + g * 16) ^ rdx));
            __builtin_amdgcn_s_setprio(1);
            #pragma unroll
            for (int c8 = 0; c8 < 8; c8++) {
                const int vrb = (c8 * 16 + l16) * 128 + g * 16;
                #pragma unroll
                for (int kc = 0; kc < 2; kc++) {
                    bf16x8 vf = *(const bf16x8*)(vsb + ((vrb + kc * 64) ^ rdx));
                    o[c8] = __builtin_amdgcn_mfma_f32_16x16x32_bf16(pf[kc], vf, o[c8], 0, 0, 0);
                }
            }
            __builtin_amdgcn_s_setprio(0);
        }

        #pragma unroll
        for (int i = 0; i < 4; i++) {
            float ls = lv[i];
            ls += __shfl_xor(ls, 1);
            ls += __shfl_xor(ls, 2);
            ls += __shfl_xor(ls, 4);
            ls += __shfl_xor(ls, 8);
            float inv = 1.0f / ls;
            int qrow = qb + w * 16 + g * 4 + i;
            size_t rb = ((size_t)(b * NL + qrow)) * ND + h * NDK;
            #pragma unroll
            for (int c8 = 0; c8 < 8; c8++)
                attn_out[rb + c8 * 16 + l16] = f2bf(o[c8][i] * inv);
        }
    }
}

__global__ void ws_signature_kernel(float* y) { if (threadIdx.x == 0) y[0] = 12345.0f; }

extern "C" void kernel_launch(void* const* d_in, const int* in_sizes, int n_in,
                              void* d_out, int out_size, void* d_ws, size_t ws_size,
                              hipStream_t stream)
{
    const float* x     = (const float*)d_in[0];
    const float* w_qkv = (const float*)d_in[1];
    const float* w_o   = (const float*)d_in[2];
    const float* ct    = (const float*)d_in[3];
    const float* st    = (const float*)d_in[4];

    const size_t NTOK = (size_t)NB * NL * ND;
    float* y_out = (float*)d_out;
    float* k_out = y_out + NTOK;
    float* v_out = y_out + 2 * NTOK;

    const size_t need = (6 * NTOK + 4 * (size_t)ND * ND) * sizeof(unsigned short);
    if (ws_size < need) {
        ws_signature_kernel<<<1, 64, 0, stream>>>(y_out);
        return;
    }
    unsigned short* x_bf  = (unsigned short*)d_ws;
    unsigned short* Wt    = x_bf + NTOK;
    unsigned short* Wt_o  = Wt + (size_t)3 * ND * ND;
    unsigned short* q_raw = Wt_o + (size_t)ND * ND;
    unsigned short* q_bf  = q_raw + NTOK;        // unused (kept for layout)
    unsigned short* k_bf  = q_bf + NTOK;
    unsigned short* Vt    = k_bf + NTOK;
    unsigned short* a_bf  = Vt + NTOK;

    convert_bf16_kernel<<<4096, 256, 0, stream>>>(x, x_bf);
    transpose_convert_kernel<<<dim3(96, 32), 256, 0, stream>>>(w_qkv, Wt, ND, 3 * ND);
    transpose_convert_kernel<<<dim3(32, 32), 256, 0, stream>>>(w_o, Wt_o, ND, ND);
    gemm_bf16<0><<<1536, 256, 0, stream>>>(x_bf, Wt, nullptr, q_raw, k_out, v_out, ND, 48);
    rope_k_kernel<<<4096, 256, 0, stream>>>(k_out, k_bf, ct, st);
    transpose_v_kernel<<<dim3(2, 32, 32), 256, 0, stream>>>(v_out, Vt);
    attn_kernel<<<dim3(32, 16), 256, 0, stream>>>(q_raw, k_bf, Vt, a_bf, ct, st);
    gemm_bf16<1><<<512, 256, 0, stream>>>(a_bf, Wt_o, y_out, nullptr, nullptr, nullptr, ND, 16);
}

// Round 5
// 329.413 us; speedup vs baseline: 1.2184x; 1.1422x over previous
//
#include <hip/hip_runtime.h>
#include <hip/hip_bf16.h>

#define NB 2
#define NL 2048
#define ND 2048
#define NH 16
#define NDK 128
// SCALE * log2(e): softmax tracked in exp2 domain (saves the mul inside __expf)
#define SCALE2 0.12753102866606474f

#define AS1 __attribute__((address_space(1)))
#define AS3 __attribute__((address_space(3)))

typedef __attribute__((ext_vector_type(8))) __bf16 bf16x8;
typedef __attribute__((ext_vector_type(4))) float f32x4;

__device__ __forceinline__ unsigned short f2bf(float f) {
    union { float f; unsigned u; } v; v.f = f;
    return (unsigned short)((v.u + 0x7fffu + ((v.u >> 16) & 1u)) >> 16);
}
__device__ __forceinline__ float bf2f(unsigned short h) {
    union { unsigned u; float f; } v; v.u = ((unsigned)h) << 16;
    return v.f;
}

// ============ fp32 -> bf16 flat convert (x) =============================================
__global__ __launch_bounds__(256)
void convert_bf16_kernel(const float* __restrict__ in, unsigned short* __restrict__ outp)
{
    int i = blockIdx.x * 256 + threadIdx.x;
    const float4 a = ((const float4*)in)[2 * i];
    const float4 b = ((const float4*)in)[2 * i + 1];
    unsigned short t[8] = { f2bf(a.x), f2bf(a.y), f2bf(a.z), f2bf(a.w),
                            f2bf(b.x), f2bf(b.y), f2bf(b.z), f2bf(b.w) };
    ((uint4*)outp)[i] = *(uint4*)t;
}

// ============ fp32 (R x C) -> bf16 transposed (C x R), 64x64 LDS tiles ==================
__global__ __launch_bounds__(256)
void transpose_convert_kernel(const float* __restrict__ in, unsigned short* __restrict__ outp,
                              int R, int C)
{
    __shared__ float T[64][65];
    const int tr0 = blockIdx.y * 64;
    const int tc0 = blockIdx.x * 64;
    const int t = threadIdx.x;
    const int r = t >> 2;
    const int q = t & 3;
    const float* src = in + (size_t)(tr0 + r) * C + tc0 + q * 16;
    #pragma unroll
    for (int i = 0; i < 4; i++) {
        float4 f = *(const float4*)(src + 4 * i);
        T[r][q * 16 + 4 * i + 0] = f.x;
        T[r][q * 16 + 4 * i + 1] = f.y;
        T[r][q * 16 + 4 * i + 2] = f.z;
        T[r][q * 16 + 4 * i + 3] = f.w;
    }
    __syncthreads();
    unsigned short tmp[16];
    #pragma unroll
    for (int i = 0; i < 16; i++) tmp[i] = f2bf(T[q * 16 + i][r]);
    unsigned short* dst = outp + (size_t)(tc0 + r) * R + tr0 + q * 16;
    *(uint4*)dst       = *(uint4*)&tmp[0];
    *(uint4*)(dst + 8) = *(uint4*)&tmp[8];
}

// ============ per-head V transpose: v fp32 (BH, L, DK) -> Vt bf16 (BH, DK, L) ===========
__global__ __launch_bounds__(256)
void transpose_v_kernel(const float* __restrict__ v, unsigned short* __restrict__ vt)
{
    __shared__ float T[64][65];
    const int bh = blockIdx.z;
    const int l0 = blockIdx.y * 64;
    const int d0 = blockIdx.x * 64;
    const int t = threadIdx.x;
    const int r = t >> 2;
    const int q = t & 3;
    const float* src = v + (size_t)bh * NL * NDK + (size_t)(l0 + r) * NDK + d0 + q * 16;
    #pragma unroll
    for (int i = 0; i < 4; i++) {
        float4 f = *(const float4*)(src + 4 * i);
        T[r][q * 16 + 4 * i + 0] = f.x;
        T[r][q * 16 + 4 * i + 1] = f.y;
        T[r][q * 16 + 4 * i + 2] = f.z;
        T[r][q * 16 + 4 * i + 3] = f.w;
    }
    __syncthreads();
    unsigned short tmp[16];
    #pragma unroll
    for (int i = 0; i < 16; i++) tmp[i] = f2bf(T[q * 16 + i][r]);
    unsigned short* dst = vt + (size_t)bh * NDK * NL + (size_t)(d0 + r) * NL + l0 + q * 16;
    *(uint4*)dst       = *(uint4*)&tmp[0];
    *(uint4*)(dst + 8) = *(uint4*)&tmp[8];
}

// ============ pipelined bf16 GEMM (validated round 10): C = A @ Bt^T ====================
template<int EPI>
__global__ __launch_bounds__(256)
void gemm_bf16(const unsigned short* __restrict__ A, const unsigned short* __restrict__ Bt,
               float* __restrict__ y_dst,
               unsigned short* __restrict__ q_raw,
               float* __restrict__ k_dst, float* __restrict__ v_dst,
               int K, int NT)
{
    __shared__ __align__(16) unsigned short As[3][128][32];
    __shared__ __align__(16) unsigned short Bs[3][128][32];

    const int tid = threadIdx.x;
    const int lane = tid & 63;
    const int l16 = lane & 15, g = lane >> 4;
    const int w = tid >> 6;
    const int wr = w >> 1, wc = w & 1;

    const int cpn = NT >> 3;
    const int bid = blockIdx.x;
    const int xcd = bid & 7, local = bid >> 3;
    const int bx = xcd * cpn + local % cpn;
    const int by = local / cpn;
    const int m0 = by * 128, n0 = bx * 128;

    const int rowl = (w << 4) + (lane >> 2);
    const int swl = (rowl >> 1) & 3;
    const int kofl = ((lane & 3) ^ swl) << 3;
    const unsigned short* gA = A + (size_t)(m0 + rowl) * K + kofl;
    const unsigned short* gB = Bt + (size_t)(n0 + rowl) * K + kofl;
    const int ldsoff = (w << 10) + (lane << 4);

    f32x4 acc[4][4] = {};
    const int NTILES = K >> 5;

    auto STAGE = [&](int t, int buf) {
        const int k0 = t << 5;
        char* baseA = (char*)&As[buf][0][0] + ldsoff;
        char* baseB = (char*)&Bs[buf][0][0] + ldsoff;
        #pragma unroll
        for (int i = 0; i < 2; i++) {
            __builtin_amdgcn_global_load_lds((const AS1 void*)(gA + (size_t)i * 64 * K + k0),
                                             (AS3 void*)(baseA + i * 4096), 16, 0, 0);
            __builtin_amdgcn_global_load_lds((const AS1 void*)(gB + (size_t)i * 64 * K + k0),
                                             (AS3 void*)(baseB + i * 4096), 16, 0, 0);
        }
    };

    const int rsw = (l16 >> 1) & 3;

    STAGE(0, 0); STAGE(1, 1);

    int bufC = 0;
    for (int t = 0; t < NTILES; t++) {
        const int bufS = (bufC == 0) ? 2 : bufC - 1;
        if (t + 2 < NTILES) STAGE(t + 2, bufS);
        if (t + 2 < NTILES)      asm volatile("s_waitcnt vmcnt(8)" ::: "memory");
        else if (t + 1 < NTILES) asm volatile("s_waitcnt vmcnt(4)" ::: "memory");
        else                     asm volatile("s_waitcnt vmcnt(0)" ::: "memory");
        __builtin_amdgcn_s_barrier();
        __builtin_amdgcn_sched_barrier(0);

        const char* pa = (const char*)&As[bufC][0][0];
        const char* pb = (const char*)&Bs[bufC][0][0];
        bf16x8 af[4], bfr[4];
        #pragma unroll
        for (int r = 0; r < 4; r++) {
            int row = wr * 64 + r * 16 + l16;
            af[r] = *(const bf16x8*)(pa + row * 64 + ((g ^ rsw) << 4));
        }
        #pragma unroll
        for (int c = 0; c < 4; c++) {
            int row = wc * 64 + c * 16 + l16;
            bfr[c] = *(const bf16x8*)(pb + row * 64 + ((g ^ rsw) << 4));
        }
        #pragma unroll
        for (int r = 0; r < 4; r++)
            #pragma unroll
            for (int c = 0; c < 4; c++)
                acc[r][c] = __builtin_amdgcn_mfma_f32_16x16x32_bf16(af[r], bfr[c], acc[r][c], 0, 0, 0);

        __builtin_amdgcn_s_barrier();
        __builtin_amdgcn_sched_barrier(0);
        bufC = (bufC == 2) ? 0 : bufC + 1;
    }

    if constexpr (EPI == 0) {
        const int m3 = bx >> 4, h = bx & 15;
        #pragma unroll
        for (int r = 0; r < 4; r++) {
            int mrow = m0 + wr * 64 + r * 16 + g * 4;
            int b = mrow >> 11, l = mrow & 2047;
            size_t rb = ((size_t)(b * NH + h) * NL + l) * NDK;
            #pragma unroll
            for (int c = 0; c < 4; c++) {
                int dk = wc * 64 + c * 16 + l16;
                #pragma unroll
                for (int i = 0; i < 4; i++) {
                    float val = acc[r][c][i];
                    size_t off = rb + (size_t)i * NDK + dk;
                    if (m3 == 0) q_raw[off] = f2bf(val);
                    else if (m3 == 1) k_dst[off] = val;
                    else v_dst[off] = val;
                }
            }
        }
    } else {
        #pragma unroll
        for (int r = 0; r < 4; r++) {
            int mrow = m0 + wr * 64 + r * 16 + g * 4;
            #pragma unroll
            for (int c = 0; c < 4; c++) {
                int ncol = n0 + wc * 64 + c * 16 + l16;
                #pragma unroll
                for (int i = 0; i < 4; i++)
                    y_dst[(size_t)(mrow + i) * ND + ncol] = acc[r][c][i];
            }
        }
    }
}

// ============ RoPE on k only: fp32 in-place (final) + bf16 copy, float4-vectorized ======
__global__ __launch_bounds__(256)
void rope_k_kernel(float* __restrict__ kp, unsigned short* __restrict__ k_bf,
                   const float* __restrict__ ct, const float* __restrict__ st)
{
    int idx = blockIdx.x * 256 + threadIdx.x;
    int d = (idx & 15) << 2;
    int rr = idx >> 4;
    size_t ro = (size_t)rr * NDK;
    int l = rr & (NL - 1);
    float4 c  = *(const float4*)(ct + l * 64 + d);
    float4 s  = *(const float4*)(st + l * 64 + d);
    float4 t1 = *(const float4*)(kp + ro + d);
    float4 t2 = *(const float4*)(kp + ro + d + 64);
    float4 o1, o2;
    o1.x = t1.x * c.x - t2.x * s.x;  o2.x = t1.x * s.x + t2.x * c.x;
    o1.y = t1.y * c.y - t2.y * s.y;  o2.y = t1.y * s.y + t2.y * c.y;
    o1.z = t1.z * c.z - t2.z * s.z;  o2.z = t1.z * s.z + t2.z * c.z;
    o1.w = t1.w * c.w - t2.w * s.w;  o2.w = t1.w * s.w + t2.w * c.w;
    *(float4*)(kp + ro + d)      = o1;
    *(float4*)(kp + ro + d + 64) = o2;
    unsigned short u1[4] = { f2bf(o1.x), f2bf(o1.y), f2bf(o1.z), f2bf(o1.w) };
    unsigned short u2[4] = { f2bf(o2.x), f2bf(o2.y), f2bf(o2.z), f2bf(o2.w) };
    *(uint2*)(k_bf + ro + d)      = *(uint2*)u1;
    *(uint2*)(k_bf + ro + d + 64) = *(uint2*)u2;
}

// ============ MFMA flash attention (round-0 validated structure, one Q-tile per block) ==
// grid (32 bh, 32 jq-slots); jq = 31 - blockIdx.y so heavy blocks dispatch first
// (triangular causal work backfills with light blocks). 1024 blocks -> 3 resident/CU
// (VGPR-capped) vs 2 before: more latency hiding for this latency-bound kernel.
// Softmax in exp2 domain (SCALE2 = SCALE*log2e): v_exp_f32 without the inner mul.
// T13 REVERTED (round-4 post-mortem: branch around o-rescale -> rule #20 scratch spill).
__global__ __launch_bounds__(256)
void attn_kernel(const unsigned short* __restrict__ q,
                 const unsigned short* __restrict__ k,
                 const unsigned short* __restrict__ vt,
                 unsigned short* __restrict__ attn_out,
                 const float* __restrict__ ct, const float* __restrict__ st)
{
    __shared__ __align__(16) unsigned short Ks[64][128];
    __shared__ __align__(16) unsigned short Vts[128][64];
    __shared__ __align__(16) unsigned short Ps[4][16][64];

    char* const ksb = (char*)&Ks[0][0];
    char* const vsb = (char*)&Vts[0][0];
    char* const psb = (char*)&Ps[0][0][0];

    const int tid = threadIdx.x, lane = tid & 63, w = tid >> 6;
    const int l16 = lane & 15, g = lane >> 4;
    const int bh = blockIdx.x;
    const int b = bh >> 4, h = bh & 15;
    const size_t base = (size_t)bh * NL * NDK;

    const int krow = tid >> 2;
    const int kq = tid & 3;
    const int kwb = krow * 256 + kq * 64;
    const int kwx = (krow & 7) << 4;
    const int vrow = tid >> 1;
    const int vh = tid & 1;
    const int vwb = vrow * 128 + vh * 64;
    const int vwx = (vrow & 7) << 4;

    const int rdx = (l16 & 7) << 4;

    const unsigned short* const kbase = k + base + (size_t)krow * NDK + kq * 32;
    const unsigned short* const vbase = vt + base + (size_t)vrow * NL + vh * 32;

    const int jq = 31 - (int)blockIdx.y;      // heavy first
    const int qb = jq * 64;

    // ---- Q load with fused RoPE ----
    bf16x8 aq[4];
    {
        const int l = qb + w * 16 + l16;
        const unsigned short* src = q + base + (size_t)l * NDK + g * 8;
        union { bf16x8 v; unsigned short s[8]; } raw[4], outv[4];
        #pragma unroll
        for (int ks2 = 0; ks2 < 4; ks2++) raw[ks2].v = *(const bf16x8*)(src + ks2 * 32);
        const float* cb = ct + (size_t)l * 64 + g * 8;
        const float* sb = st + (size_t)l * 64 + g * 8;
        float cv[2][8], sv2[2][8];
        #pragma unroll
        for (int hh = 0; hh < 2; hh++) {
            float4 c0 = *(const float4*)(cb + 32 * hh);
            float4 c1 = *(const float4*)(cb + 32 * hh + 4);
            float4 s0 = *(const float4*)(sb + 32 * hh);
            float4 s1 = *(const float4*)(sb + 32 * hh + 4);
            cv[hh][0]=c0.x; cv[hh][1]=c0.y; cv[hh][2]=c0.z; cv[hh][3]=c0.w;
            cv[hh][4]=c1.x; cv[hh][5]=c1.y; cv[hh][6]=c1.z; cv[hh][7]=c1.w;
            sv2[hh][0]=s0.x; sv2[hh][1]=s0.y; sv2[hh][2]=s0.z; sv2[hh][3]=s0.w;
            sv2[hh][4]=s1.x; sv2[hh][5]=s1.y; sv2[hh][6]=s1.z; sv2[hh][7]=s1.w;
        }
        #pragma unroll
        for (int hh = 0; hh < 2; hh++)
            #pragma unroll
            for (int j = 0; j < 8; j++) {
                float t1 = bf2f(raw[hh].s[j]), t2 = bf2f(raw[hh + 2].s[j]);
                float c = cv[hh][j], s = sv2[hh][j];
                outv[hh].s[j]     = f2bf(t1 * c - t2 * s);
                outv[hh + 2].s[j] = f2bf(t1 * s + t2 * c);
            }
        #pragma unroll
        for (int ks2 = 0; ks2 < 4; ks2++) aq[ks2] = outv[ks2].v;
    }

    f32x4 o[8] = {};
    float m_r[4], lv[4];
    #pragma unroll
    for (int i = 0; i < 4; i++) { m_r[i] = -1e30f; lv[i] = 0.f; }

    // ---- T14 prologue: tile 0 into named registers ----
    uint4 pk0, pk1, pk2, pk3, pv0, pv1, pv2, pv3;
    {
        const unsigned short* ks = kbase;           // kv0 = 0
        pk0 = *(const uint4*)(ks);
        pk1 = *(const uint4*)(ks + 8);
        pk2 = *(const uint4*)(ks + 16);
        pk3 = *(const uint4*)(ks + 24);
        const unsigned short* vs = vbase;
        pv0 = *(const uint4*)(vs);
        pv1 = *(const uint4*)(vs + 8);
        pv2 = *(const uint4*)(vs + 16);
        pv3 = *(const uint4*)(vs + 24);
    }

    for (int kv0 = 0; kv0 <= qb; kv0 += 64) {
        __syncthreads();                    // prior reads done; vmcnt(0) lands prefetch
        *(uint4*)(ksb + ((kwb     ) ^ kwx)) = pk0;
        *(uint4*)(ksb + ((kwb + 16) ^ kwx)) = pk1;
        *(uint4*)(ksb + ((kwb + 32) ^ kwx)) = pk2;
        *(uint4*)(ksb + ((kwb + 48) ^ kwx)) = pk3;
        *(uint4*)(vsb + ((vwb     ) ^ vwx)) = pv0;
        *(uint4*)(vsb + ((vwb + 16) ^ vwx)) = pv1;
        *(uint4*)(vsb + ((vwb + 32) ^ vwx)) = pv2;
        *(uint4*)(vsb + ((vwb + 48) ^ vwx)) = pv3;
        __syncthreads();                    // LDS tile visible to all waves

        if (kv0 + 64 <= qb) {               // T14: issue next tile now (inline, named)
            const unsigned short* ks = kbase + (size_t)(kv0 + 64) * NDK;
            pk0 = *(const uint4*)(ks);
            pk1 = *(const uint4*)(ks + 8);
            pk2 = *(const uint4*)(ks + 16);
            pk3 = *(const uint4*)(ks + 24);
            const unsigned short* vs = vbase + kv0 + 64;
            pv0 = *(const uint4*)(vs);
            pv1 = *(const uint4*)(vs + 8);
            pv2 = *(const uint4*)(vs + 16);
            pv3 = *(const uint4*)(vs + 24);
            __builtin_amdgcn_sched_barrier(0);  // pin issue point before compute
        }

        // ---- QK^T: 16 MFMAs ----
        f32x4 sv[4];
        __builtin_amdgcn_s_setprio(1);
        #pragma unroll
        for (int cf = 0; cf < 4; cf++) {
            const int krb = (cf * 16 + l16) * 256 + g * 16;
            f32x4 a = {};
            #pragma unroll
            for (int ks2 = 0; ks2 < 4; ks2++) {
                bf16x8 kf = *(const bf16x8*)(ksb + ((krb + 64 * ks2) ^ rdx));
                a = __builtin_amdgcn_mfma_f32_16x16x32_bf16(aq[ks2], kf, a, 0, 0, 0);
            }
            sv[cf] = a;
        }
        __builtin_amdgcn_s_setprio(0);

        // ---- online softmax (exp2 domain, deferred l-sum) ----
        const int kvl = kv0 + l16;
        const int rowb = qb + w * 16 + g * 4;
        #pragma unroll
        for (int i = 0; i < 4; i++) {
            int row = rowb + i;
            float s0 = sv[0][i] * SCALE2;
            float s1 = sv[1][i] * SCALE2;
            float s2 = sv[2][i] * SCALE2;
            float s3 = sv[3][i] * SCALE2;
            if (kvl      > row) s0 = -1e30f;
            if (kvl + 16 > row) s1 = -1e30f;
            if (kvl + 32 > row) s2 = -1e30f;
            if (kvl + 48 > row) s3 = -1e30f;
            float mx = fmaxf(fmaxf(s0, s1), fmaxf(s2, s3));
            mx = fmaxf(mx, __shfl_xor(mx, 1));
            mx = fmaxf(mx, __shfl_xor(mx, 2));
            mx = fmaxf(mx, __shfl_xor(mx, 4));
            mx = fmaxf(mx, __shfl_xor(mx, 8));
            float mnew = fmaxf(m_r[i], mx);
            float fac = exp2f(m_r[i] - mnew);
            float p0 = exp2f(s0 - mnew);
            float p1 = exp2f(s1 - mnew);
            float p2 = exp2f(s2 - mnew);
            float p3 = exp2f(s3 - mnew);
            lv[i] = lv[i] * fac + ((p0 + p1) + (p2 + p3));
            m_r[i] = mnew;
            #pragma unroll
            for (int c8 = 0; c8 < 8; c8++) o[c8][i] *= fac;
            const int pr = g * 4 + i;
            char* pw = psb + w * 2048 + pr * 128;
            const int px = (pr & 7) << 4;
            const int cb2 = l16 << 1;
            *(unsigned short*)(pw + ((cb2)      ^ px)) = f2bf(p0);
            *(unsigned short*)(pw + ((cb2 + 32) ^ px)) = f2bf(p1);
            *(unsigned short*)(pw + ((cb2 + 64) ^ px)) = f2bf(p2);
            *(unsigned short*)(pw + ((cb2 + 96) ^ px)) = f2bf(p3);
        }
        // wave-local LDS RAW (Ps write -> cross-lane read): drain + pin (rule #18)
        asm volatile("s_waitcnt lgkmcnt(0)" ::: "memory");
        __builtin_amdgcn_sched_barrier(0);

        // ---- PV: 16 MFMAs ----
        bf16x8 pf[2];
        #pragma unroll
        for (int kc = 0; kc < 2; kc++)
            pf[kc] = *(const bf16x8*)(psb + w * 2048 + l16 * 128 + ((kc * 64 + g * 16) ^ rdx));
        __builtin_amdgcn_s_setprio(1);
        #pragma unroll
        for (int c8 = 0; c8 < 8; c8++) {
            const int vrb = (c8 * 16 + l16) * 128 + g * 16;
            #pragma unroll
            for (int kc = 0; kc < 2; kc++) {
                bf16x8 vf = *(const bf16x8*)(vsb + ((vrb + kc * 64) ^ rdx));
                o[c8] = __builtin_amdgcn_mfma_f32_16x16x32_bf16(pf[kc], vf, o[c8], 0, 0, 0);
            }
        }
        __builtin_amdgcn_s_setprio(0);
    }

    #pragma unroll
    for (int i = 0; i < 4; i++) {
        float ls = lv[i];
        ls += __shfl_xor(ls, 1);
        ls += __shfl_xor(ls, 2);
        ls += __shfl_xor(ls, 4);
        ls += __shfl_xor(ls, 8);
        float inv = 1.0f / ls;
        int qrow = qb + w * 16 + g * 4 + i;
        size_t rb = ((size_t)(b * NL + qrow)) * ND + h * NDK;
        #pragma unroll
        for (int c8 = 0; c8 < 8; c8++)
            attn_out[rb + c8 * 16 + l16] = f2bf(o[c8][i] * inv);
    }
}

__global__ void ws_signature_kernel(float* y) { if (threadIdx.x == 0) y[0] = 12345.0f; }

extern "C" void kernel_launch(void* const* d_in, const int* in_sizes, int n_in,
                              void* d_out, int out_size, void* d_ws, size_t ws_size,
                              hipStream_t stream)
{
    const float* x     = (const float*)d_in[0];
    const float* w_qkv = (const float*)d_in[1];
    const float* w_o   = (const float*)d_in[2];
    const float* ct    = (const float*)d_in[3];
    const float* st    = (const float*)d_in[4];

    const size_t NTOK = (size_t)NB * NL * ND;
    float* y_out = (float*)d_out;
    float* k_out = y_out + NTOK;
    float* v_out = y_out + 2 * NTOK;

    const size_t need = (6 * NTOK + 4 * (size_t)ND * ND) * sizeof(unsigned short);
    if (ws_size < need) {
        ws_signature_kernel<<<1, 64, 0, stream>>>(y_out);
        return;
    }
    unsigned short* x_bf  = (unsigned short*)d_ws;
    unsigned short* Wt    = x_bf + NTOK;
    unsigned short* Wt_o  = Wt + (size_t)3 * ND * ND;
    unsigned short* q_raw = Wt_o + (size_t)ND * ND;
    unsigned short* q_bf  = q_raw + NTOK;        // unused (kept for layout)
    unsigned short* k_bf  = q_bf + NTOK;
    unsigned short* Vt    = k_bf + NTOK;
    unsigned short* a_bf  = Vt + NTOK;

    convert_bf16_kernel<<<4096, 256, 0, stream>>>(x, x_bf);
    transpose_convert_kernel<<<dim3(96, 32), 256, 0, stream>>>(w_qkv, Wt, ND, 3 * ND);
    transpose_convert_kernel<<<dim3(32, 32), 256, 0, stream>>>(w_o, Wt_o, ND, ND);
    gemm_bf16<0><<<1536, 256, 0, stream>>>(x_bf, Wt, nullptr, q_raw, k_out, v_out, ND, 48);
    rope_k_kernel<<<4096, 256, 0, stream>>>(k_out, k_bf, ct, st);
    transpose_v_kernel<<<dim3(2, 32, 32), 256, 0, stream>>>(v_out, Vt);
    attn_kernel<<<dim3(32, 32), 256, 0, stream>>>(q_raw, k_bf, Vt, a_bf, ct, st);
    gemm_bf16<1><<<512, 256, 0, stream>>>(a_bf, Wt_o, y_out, nullptr, nullptr, nullptr, ND, 16);
}

// Round 6
// 325.617 us; speedup vs baseline: 1.2326x; 1.0117x over previous
//
#include <hip/hip_runtime.h>
#include <hip/hip_bf16.h>

#define NB 2
#define NL 2048
#define ND 2048
#define NH 16
#define NDK 128
// SCALE * log2(e): softmax tracked in exp2 domain (saves the mul inside __expf)
#define SCALE2 0.12753102866606474f

#define AS1 __attribute__((address_space(1)))
#define AS3 __attribute__((address_space(3)))

typedef __attribute__((ext_vector_type(8))) __bf16 bf16x8;
typedef __attribute__((ext_vector_type(4))) float f32x4;

__device__ __forceinline__ unsigned short f2bf(float f) {
    union { float f; unsigned u; } v; v.f = f;
    return (unsigned short)((v.u + 0x7fffu + ((v.u >> 16) & 1u)) >> 16);
}
__device__ __forceinline__ float bf2f(unsigned short h) {
    union { unsigned u; float f; } v; v.u = ((unsigned)h) << 16;
    return v.f;
}

// ============ fp32 -> bf16 flat convert (x) =============================================
__global__ __launch_bounds__(256)
void convert_bf16_kernel(const float* __restrict__ in, unsigned short* __restrict__ outp)
{
    int i = blockIdx.x * 256 + threadIdx.x;
    const float4 a = ((const float4*)in)[2 * i];
    const float4 b = ((const float4*)in)[2 * i + 1];
    unsigned short t[8] = { f2bf(a.x), f2bf(a.y), f2bf(a.z), f2bf(a.w),
                            f2bf(b.x), f2bf(b.y), f2bf(b.z), f2bf(b.w) };
    ((uint4*)outp)[i] = *(uint4*)t;
}

// ============ fp32 (R x C) -> bf16 transposed (C x R), 64x64 LDS tiles ==================
__global__ __launch_bounds__(256)
void transpose_convert_kernel(const float* __restrict__ in, unsigned short* __restrict__ outp,
                              int R, int C)
{
    __shared__ float T[64][65];
    const int tr0 = blockIdx.y * 64;
    const int tc0 = blockIdx.x * 64;
    const int t = threadIdx.x;
    const int r = t >> 2;
    const int q = t & 3;
    const float* src = in + (size_t)(tr0 + r) * C + tc0 + q * 16;
    #pragma unroll
    for (int i = 0; i < 4; i++) {
        float4 f = *(const float4*)(src + 4 * i);
        T[r][q * 16 + 4 * i + 0] = f.x;
        T[r][q * 16 + 4 * i + 1] = f.y;
        T[r][q * 16 + 4 * i + 2] = f.z;
        T[r][q * 16 + 4 * i + 3] = f.w;
    }
    __syncthreads();
    unsigned short tmp[16];
    #pragma unroll
    for (int i = 0; i < 16; i++) tmp[i] = f2bf(T[q * 16 + i][r]);
    unsigned short* dst = outp + (size_t)(tc0 + r) * R + tr0 + q * 16;
    *(uint4*)dst       = *(uint4*)&tmp[0];
    *(uint4*)(dst + 8) = *(uint4*)&tmp[8];
}

// ============ per-head V transpose: v fp32 (BH, L, DK) -> Vt bf16 (BH, DK, L) ===========
__global__ __launch_bounds__(256)
void transpose_v_kernel(const float* __restrict__ v, unsigned short* __restrict__ vt)
{
    __shared__ float T[64][65];
    const int bh = blockIdx.z;
    const int l0 = blockIdx.y * 64;
    const int d0 = blockIdx.x * 64;
    const int t = threadIdx.x;
    const int r = t >> 2;
    const int q = t & 3;
    const float* src = v + (size_t)bh * NL * NDK + (size_t)(l0 + r) * NDK + d0 + q * 16;
    #pragma unroll
    for (int i = 0; i < 4; i++) {
        float4 f = *(const float4*)(src + 4 * i);
        T[r][q * 16 + 4 * i + 0] = f.x;
        T[r][q * 16 + 4 * i + 1] = f.y;
        T[r][q * 16 + 4 * i + 2] = f.z;
        T[r][q * 16 + 4 * i + 3] = f.w;
    }
    __syncthreads();
    unsigned short tmp[16];
    #pragma unroll
    for (int i = 0; i < 16; i++) tmp[i] = f2bf(T[q * 16 + i][r]);
    unsigned short* dst = vt + (size_t)bh * NDK * NL + (size_t)(d0 + r) * NL + l0 + q * 16;
    *(uint4*)dst       = *(uint4*)&tmp[0];
    *(uint4*)(dst + 8) = *(uint4*)&tmp[8];
}

// ============ pipelined bf16 GEMM: C = A @ Bt^T — single barrier per K-step =============
// Round-6 change: removed the post-MFMA barrier. Safety argument:
//  - bar1(t) (after vmcnt) publishes tile t. Any wave past bar1(t) has finished its
//    iteration t-1 ds_reads (compiler lgkm-waits them before the t-1 MFMAs, which
//    precede bar1(t) in program order).
//  - STAGE(t+2) targets buf (t+2)%3 = buffer last READ at iteration t-1 -> issuing it
//    AFTER bar1(t) is WAR-safe across waves with no second barrier.
//  - vmcnt: 8 issues outstanding at iteration top (tiles t, t+1); vmcnt(4) drains tile t;
//    vmcnt(0) on the last iteration only. Staging now overlaps the MFMA block.
template<int EPI>
__global__ __launch_bounds__(256)
void gemm_bf16(const unsigned short* __restrict__ A, const unsigned short* __restrict__ Bt,
               float* __restrict__ y_dst,
               unsigned short* __restrict__ q_raw,
               float* __restrict__ k_dst, float* __restrict__ v_dst,
               int K, int NT)
{
    __shared__ __align__(16) unsigned short As[3][128][32];
    __shared__ __align__(16) unsigned short Bs[3][128][32];

    const int tid = threadIdx.x;
    const int lane = tid & 63;
    const int l16 = lane & 15, g = lane >> 4;
    const int w = tid >> 6;
    const int wr = w >> 1, wc = w & 1;

    const int cpn = NT >> 3;
    const int bid = blockIdx.x;
    const int xcd = bid & 7, local = bid >> 3;
    const int bx = xcd * cpn + local % cpn;
    const int by = local / cpn;
    const int m0 = by * 128, n0 = bx * 128;

    const int rowl = (w << 4) + (lane >> 2);
    const int swl = (rowl >> 1) & 3;
    const int kofl = ((lane & 3) ^ swl) << 3;
    const unsigned short* gA = A + (size_t)(m0 + rowl) * K + kofl;
    const unsigned short* gB = Bt + (size_t)(n0 + rowl) * K + kofl;
    const int ldsoff = (w << 10) + (lane << 4);

    f32x4 acc[4][4] = {};
    const int NTILES = K >> 5;

    auto STAGE = [&](int t, int buf) {
        const int k0 = t << 5;
        char* baseA = (char*)&As[buf][0][0] + ldsoff;
        char* baseB = (char*)&Bs[buf][0][0] + ldsoff;
        #pragma unroll
        for (int i = 0; i < 2; i++) {
            __builtin_amdgcn_global_load_lds((const AS1 void*)(gA + (size_t)i * 64 * K + k0),
                                             (AS3 void*)(baseA + i * 4096), 16, 0, 0);
            __builtin_amdgcn_global_load_lds((const AS1 void*)(gB + (size_t)i * 64 * K + k0),
                                             (AS3 void*)(baseB + i * 4096), 16, 0, 0);
        }
    };

    const int rsw = (l16 >> 1) & 3;

    STAGE(0, 0); STAGE(1, 1);

    int bufC = 0;
    for (int t = 0; t < NTILES; t++) {
        if (t + 1 < NTILES) asm volatile("s_waitcnt vmcnt(4)" ::: "memory");
        else                asm volatile("s_waitcnt vmcnt(0)" ::: "memory");
        __builtin_amdgcn_s_barrier();
        __builtin_amdgcn_sched_barrier(0);      // nothing (esp. ds_read) hoists above bar1

        const int bufS = (bufC == 0) ? 2 : bufC - 1;   // = (t+2)%3, read at iter t-1
        if (t + 2 < NTILES) STAGE(t + 2, bufS);

        const char* pa = (const char*)&As[bufC][0][0];
        const char* pb = (const char*)&Bs[bufC][0][0];
        bf16x8 af[4], bfr[4];
        #pragma unroll
        for (int r = 0; r < 4; r++) {
            int row = wr * 64 + r * 16 + l16;
            af[r] = *(const bf16x8*)(pa + row * 64 + ((g ^ rsw) << 4));
        }
        #pragma unroll
        for (int c = 0; c < 4; c++) {
            int row = wc * 64 + c * 16 + l16;
            bfr[c] = *(const bf16x8*)(pb + row * 64 + ((g ^ rsw) << 4));
        }
        #pragma unroll
        for (int r = 0; r < 4; r++)
            #pragma unroll
            for (int c = 0; c < 4; c++)
                acc[r][c] = __builtin_amdgcn_mfma_f32_16x16x32_bf16(af[r], bfr[c], acc[r][c], 0, 0, 0);

        bufC = (bufC == 2) ? 0 : bufC + 1;
    }

    if constexpr (EPI == 0) {
        const int m3 = bx >> 4, h = bx & 15;
        #pragma unroll
        for (int r = 0; r < 4; r++) {
            int mrow = m0 + wr * 64 + r * 16 + g * 4;
            int b = mrow >> 11, l = mrow & 2047;
            size_t rb = ((size_t)(b * NH + h) * NL + l) * NDK;
            #pragma unroll
            for (int c = 0; c < 4; c++) {
                int dk = wc * 64 + c * 16 + l16;
                #pragma unroll
                for (int i = 0; i < 4; i++) {
                    float val = acc[r][c][i];
                    size_t off = rb + (size_t)i * NDK + dk;
                    if (m3 == 0) q_raw[off] = f2bf(val);
                    else if (m3 == 1) k_dst[off] = val;
                    else v_dst[off] = val;
                }
            }
        }
    } else {
        #pragma unroll
        for (int r = 0; r < 4; r++) {
            int mrow = m0 + wr * 64 + r * 16 + g * 4;
            #pragma unroll
            for (int c = 0; c < 4; c++) {
                int ncol = n0 + wc * 64 + c * 16 + l16;
                #pragma unroll
                for (int i = 0; i < 4; i++)
                    y_dst[(size_t)(mrow + i) * ND + ncol] = acc[r][c][i];
            }
        }
    }
}

// ============ RoPE on k only: fp32 in-place (final) + bf16 copy, float4-vectorized ======
__global__ __launch_bounds__(256)
void rope_k_kernel(float* __restrict__ kp, unsigned short* __restrict__ k_bf,
                   const float* __restrict__ ct, const float* __restrict__ st)
{
    int idx = blockIdx.x * 256 + threadIdx.x;
    int d = (idx & 15) << 2;
    int rr = idx >> 4;
    size_t ro = (size_t)rr * NDK;
    int l = rr & (NL - 1);
    float4 c  = *(const float4*)(ct + l * 64 + d);
    float4 s  = *(const float4*)(st + l * 64 + d);
    float4 t1 = *(const float4*)(kp + ro + d);
    float4 t2 = *(const float4*)(kp + ro + d + 64);
    float4 o1, o2;
    o1.x = t1.x * c.x - t2.x * s.x;  o2.x = t1.x * s.x + t2.x * c.x;
    o1.y = t1.y * c.y - t2.y * s.y;  o2.y = t1.y * s.y + t2.y * c.y;
    o1.z = t1.z * c.z - t2.z * s.z;  o2.z = t1.z * s.z + t2.z * c.z;
    o1.w = t1.w * c.w - t2.w * s.w;  o2.w = t1.w * s.w + t2.w * c.w;
    *(float4*)(kp + ro + d)      = o1;
    *(float4*)(kp + ro + d + 64) = o2;
    unsigned short u1[4] = { f2bf(o1.x), f2bf(o1.y), f2bf(o1.z), f2bf(o1.w) };
    unsigned short u2[4] = { f2bf(o2.x), f2bf(o2.y), f2bf(o2.z), f2bf(o2.w) };
    *(uint2*)(k_bf + ro + d)      = *(uint2*)u1;
    *(uint2*)(k_bf + ro + d + 64) = *(uint2*)u2;
}

// ============ MFMA flash attention (round-0 validated: paired two-half blocks) ==========
// grid (32 bh, 16 by); block does jq = 31-by then by -> every block = exactly 33 KV-tile
// units (perfect balance) + L2-warm K/V reuse between halves. Only delta vs round-0:
// softmax in exp2 domain (SCALE2 = SCALE*log2e, arithmetically identical path).
__global__ __launch_bounds__(256)
void attn_kernel(const unsigned short* __restrict__ q,
                 const unsigned short* __restrict__ k,
                 const unsigned short* __restrict__ vt,
                 unsigned short* __restrict__ attn_out,
                 const float* __restrict__ ct, const float* __restrict__ st)
{
    __shared__ __align__(16) unsigned short Ks[64][128];
    __shared__ __align__(16) unsigned short Vts[128][64];
    __shared__ __align__(16) unsigned short Ps[4][16][64];

    char* const ksb = (char*)&Ks[0][0];
    char* const vsb = (char*)&Vts[0][0];
    char* const psb = (char*)&Ps[0][0][0];

    const int tid = threadIdx.x, lane = tid & 63, w = tid >> 6;
    const int l16 = lane & 15, g = lane >> 4;
    const int bh = blockIdx.x;
    const int b = bh >> 4, h = bh & 15;
    const size_t base = (size_t)bh * NL * NDK;

    const int krow = tid >> 2;
    const int kq = tid & 3;
    const int kwb = krow * 256 + kq * 64;
    const int kwx = (krow & 7) << 4;
    const int vrow = tid >> 1;
    const int vh = tid & 1;
    const int vwb = vrow * 128 + vh * 64;
    const int vwx = (vrow & 7) << 4;

    const int rdx = (l16 & 7) << 4;

    const unsigned short* const kbase = k + base + (size_t)krow * NDK + kq * 32;
    const unsigned short* const vbase = vt + base + (size_t)vrow * NL + vh * 32;

    for (int half = 0; half < 2; half++) {
        const int jq = half ? (int)blockIdx.y : 31 - (int)blockIdx.y;
        const int qb = jq * 64;

        // ---- Q load with fused RoPE ----
        bf16x8 aq[4];
        {
            const int l = qb + w * 16 + l16;
            const unsigned short* src = q + base + (size_t)l * NDK + g * 8;
            union { bf16x8 v; unsigned short s[8]; } raw[4], outv[4];
            #pragma unroll
            for (int ks2 = 0; ks2 < 4; ks2++) raw[ks2].v = *(const bf16x8*)(src + ks2 * 32);
            const float* cb = ct + (size_t)l * 64 + g * 8;
            const float* sb = st + (size_t)l * 64 + g * 8;
            float cv[2][8], sv2[2][8];
            #pragma unroll
            for (int hh = 0; hh < 2; hh++) {
                float4 c0 = *(const float4*)(cb + 32 * hh);
                float4 c1 = *(const float4*)(cb + 32 * hh + 4);
                float4 s0 = *(const float4*)(sb + 32 * hh);
                float4 s1 = *(const float4*)(sb + 32 * hh + 4);
                cv[hh][0]=c0.x; cv[hh][1]=c0.y; cv[hh][2]=c0.z; cv[hh][3]=c0.w;
                cv[hh][4]=c1.x; cv[hh][5]=c1.y; cv[hh][6]=c1.z; cv[hh][7]=c1.w;
                sv2[hh][0]=s0.x; sv2[hh][1]=s0.y; sv2[hh][2]=s0.z; sv2[hh][3]=s0.w;
                sv2[hh][4]=s1.x; sv2[hh][5]=s1.y; sv2[hh][6]=s1.z; sv2[hh][7]=s1.w;
            }
            #pragma unroll
            for (int hh = 0; hh < 2; hh++)
                #pragma unroll
                for (int j = 0; j < 8; j++) {
                    float t1 = bf2f(raw[hh].s[j]), t2 = bf2f(raw[hh + 2].s[j]);
                    float c = cv[hh][j], s = sv2[hh][j];
                    outv[hh].s[j]     = f2bf(t1 * c - t2 * s);
                    outv[hh + 2].s[j] = f2bf(t1 * s + t2 * c);
                }
            #pragma unroll
            for (int ks2 = 0; ks2 < 4; ks2++) aq[ks2] = outv[ks2].v;
        }

        f32x4 o[8] = {};
        float m_r[4], lv[4];
        #pragma unroll
        for (int i = 0; i < 4; i++) { m_r[i] = -1e30f; lv[i] = 0.f; }

        // ---- T14 prologue: tile 0 into named registers ----
        uint4 pk0, pk1, pk2, pk3, pv0, pv1, pv2, pv3;
        {
            const unsigned short* ks = kbase;           // kv0 = 0
            pk0 = *(const uint4*)(ks);
            pk1 = *(const uint4*)(ks + 8);
            pk2 = *(const uint4*)(ks + 16);
            pk3 = *(const uint4*)(ks + 24);
            const unsigned short* vs = vbase;
            pv0 = *(const uint4*)(vs);
            pv1 = *(const uint4*)(vs + 8);
            pv2 = *(const uint4*)(vs + 16);
            pv3 = *(const uint4*)(vs + 24);
        }

        for (int kv0 = 0; kv0 <= qb; kv0 += 64) {
            __syncthreads();                    // prior reads done; vmcnt(0) lands prefetch
            *(uint4*)(ksb + ((kwb     ) ^ kwx)) = pk0;
            *(uint4*)(ksb + ((kwb + 16) ^ kwx)) = pk1;
            *(uint4*)(ksb + ((kwb + 32) ^ kwx)) = pk2;
            *(uint4*)(ksb + ((kwb + 48) ^ kwx)) = pk3;
            *(uint4*)(vsb + ((vwb     ) ^ vwx)) = pv0;
            *(uint4*)(vsb + ((vwb + 16) ^ vwx)) = pv1;
            *(uint4*)(vsb + ((vwb + 32) ^ vwx)) = pv2;
            *(uint4*)(vsb + ((vwb + 48) ^ vwx)) = pv3;
            __syncthreads();                    // LDS tile visible to all waves

            if (kv0 + 64 <= qb) {               // T14: issue next tile now (inline, named)
                const unsigned short* ks = kbase + (size_t)(kv0 + 64) * NDK;
                pk0 = *(const uint4*)(ks);
                pk1 = *(const uint4*)(ks + 8);
                pk2 = *(const uint4*)(ks + 16);
                pk3 = *(const uint4*)(ks + 24);
                const unsigned short* vs = vbase + kv0 + 64;
                pv0 = *(const uint4*)(vs);
                pv1 = *(const uint4*)(vs + 8);
                pv2 = *(const uint4*)(vs + 16);
                pv3 = *(const uint4*)(vs + 24);
                __builtin_amdgcn_sched_barrier(0);  // pin issue point before compute
            }

            // ---- QK^T: 16 MFMAs ----
            f32x4 sv[4];
            __builtin_amdgcn_s_setprio(1);
            #pragma unroll
            for (int cf = 0; cf < 4; cf++) {
                const int krb = (cf * 16 + l16) * 256 + g * 16;
                f32x4 a = {};
                #pragma unroll
                for (int ks2 = 0; ks2 < 4; ks2++) {
                    bf16x8 kf = *(const bf16x8*)(ksb + ((krb + 64 * ks2) ^ rdx));
                    a = __builtin_amdgcn_mfma_f32_16x16x32_bf16(aq[ks2], kf, a, 0, 0, 0);
                }
                sv[cf] = a;
            }
            __builtin_amdgcn_s_setprio(0);

            // ---- online softmax (exp2 domain, deferred l-sum) ----
            const int kvl = kv0 + l16;
            const int rowb = qb + w * 16 + g * 4;
            #pragma unroll
            for (int i = 0; i < 4; i++) {
                int row = rowb + i;
                float s0 = sv[0][i] * SCALE2;
                float s1 = sv[1][i] * SCALE2;
                float s2 = sv[2][i] * SCALE2;
                float s3 = sv[3][i] * SCALE2;
                if (kvl      > row) s0 = -1e30f;
                if (kvl + 16 > row) s1 = -1e30f;
                if (kvl + 32 > row) s2 = -1e30f;
                if (kvl + 48 > row) s3 = -1e30f;
                float mx = fmaxf(fmaxf(s0, s1), fmaxf(s2, s3));
                mx = fmaxf(mx, __shfl_xor(mx, 1));
                mx = fmaxf(mx, __shfl_xor(mx, 2));
                mx = fmaxf(mx, __shfl_xor(mx, 4));
                mx = fmaxf(mx, __shfl_xor(mx, 8));
                float mnew = fmaxf(m_r[i], mx);
                float fac = exp2f(m_r[i] - mnew);
                float p0 = exp2f(s0 - mnew);
                float p1 = exp2f(s1 - mnew);
                float p2 = exp2f(s2 - mnew);
                float p3 = exp2f(s3 - mnew);
                lv[i] = lv[i] * fac + ((p0 + p1) + (p2 + p3));
                m_r[i] = mnew;
                #pragma unroll
                for (int c8 = 0; c8 < 8; c8++) o[c8][i] *= fac;
                const int pr = g * 4 + i;
                char* pw = psb + w * 2048 + pr * 128;
                const int px = (pr & 7) << 4;
                const int cb2 = l16 << 1;
                *(unsigned short*)(pw + ((cb2)      ^ px)) = f2bf(p0);
                *(unsigned short*)(pw + ((cb2 + 32) ^ px)) = f2bf(p1);
                *(unsigned short*)(pw + ((cb2 + 64) ^ px)) = f2bf(p2);
                *(unsigned short*)(pw + ((cb2 + 96) ^ px)) = f2bf(p3);
            }
            // wave-local LDS RAW (Ps write -> cross-lane read): drain + pin (rule #18)
            asm volatile("s_waitcnt lgkmcnt(0)" ::: "memory");
            __builtin_amdgcn_sched_barrier(0);

            // ---- PV: 16 MFMAs ----
            bf16x8 pf[2];
            #pragma unroll
            for (int kc = 0; kc < 2; kc++)
                pf[kc] = *(const bf16x8*)(psb + w * 2048 + l16 * 128 + ((kc * 64 + g * 16) ^ rdx));
            __builtin_amdgcn_s_setprio(1);
            #pragma unroll
            for (int c8 = 0; c8 < 8; c8++) {
                const int vrb = (c8 * 16 + l16) * 128 + g * 16;
                #pragma unroll
                for (int kc = 0; kc < 2; kc++) {
                    bf16x8 vf = *(const bf16x8*)(vsb + ((vrb + kc * 64) ^ rdx));
                    o[c8] = __builtin_amdgcn_mfma_f32_16x16x32_bf16(pf[kc], vf, o[c8], 0, 0, 0);
                }
            }
            __builtin_amdgcn_s_setprio(0);
        }

        #pragma unroll
        for (int i = 0; i < 4; i++) {
            float ls = lv[i];
            ls += __shfl_xor(ls, 1);
            ls += __shfl_xor(ls, 2);
            ls += __shfl_xor(ls, 4);
            ls += __shfl_xor(ls, 8);
            float inv = 1.0f / ls;
            int qrow = qb + w * 16 + g * 4 + i;
            size_t rb = ((size_t)(b * NL + qrow)) * ND + h * NDK;
            #pragma unroll
            for (int c8 = 0; c8 < 8; c8++)
                attn_out[rb + c8 * 16 + l16] = f2bf(o[c8][i] * inv);
        }
    }
}

__global__ void ws_signature_kernel(float* y) { if (threadIdx.x == 0) y[0] = 12345.0f; }

extern "C" void kernel_launch(void* const* d_in, const int* in_sizes, int n_in,
                              void* d_out, int out_size, void* d_ws, size_t ws_size,
                              hipStream_t stream)
{
    const float* x     = (const float*)d_in[0];
    const float* w_qkv = (const float*)d_in[1];
    const float* w_o   = (const float*)d_in[2];
    const float* ct    = (const float*)d_in[3];
    const float* st    = (const float*)d_in[4];

    const size_t NTOK = (size_t)NB * NL * ND;
    float* y_out = (float*)d_out;
    float* k_out = y_out + NTOK;
    float* v_out = y_out + 2 * NTOK;

    const size_t need = (6 * NTOK + 4 * (size_t)ND * ND) * sizeof(unsigned short);
    if (ws_size < need) {
        ws_signature_kernel<<<1, 64, 0, stream>>>(y_out);
        return;
    }
    unsigned short* x_bf  = (unsigned short*)d_ws;
    unsigned short* Wt    = x_bf + NTOK;
    unsigned short* Wt_o  = Wt + (size_t)3 * ND * ND;
    unsigned short* q_raw = Wt_o + (size_t)ND * ND;
    unsigned short* q_bf  = q_raw + NTOK;        // unused (kept for layout)
    unsigned short* k_bf  = q_bf + NTOK;
    unsigned short* Vt    = k_bf + NTOK;
    unsigned short* a_bf  = Vt + NTOK;

    convert_bf16_kernel<<<4096, 256, 0, stream>>>(x, x_bf);
    transpose_convert_kernel<<<dim3(96, 32), 256, 0, stream>>>(w_qkv, Wt, ND, 3 * ND);
    transpose_convert_kernel<<<dim3(32, 32), 256, 0, stream>>>(w_o, Wt_o, ND, ND);
    gemm_bf16<0><<<1536, 256, 0, stream>>>(x_bf, Wt, nullptr, q_raw, k_out, v_out, ND, 48);
    rope_k_kernel<<<4096, 256, 0, stream>>>(k_out, k_bf, ct, st);
    transpose_v_kernel<<<dim3(2, 32, 32), 256, 0, stream>>>(v_out, Vt);
    attn_kernel<<<dim3(32, 16), 256, 0, stream>>>(q_raw, k_bf, Vt, a_bf, ct, st);
    gemm_bf16<1><<<512, 256, 0, stream>>>(a_bf, Wt_o, y_out, nullptr, nullptr, nullptr, ND, 16);
}

// Round 7
// 316.062 us; speedup vs baseline: 1.2699x; 1.0302x over previous
//
#include <hip/hip_runtime.h>
#include <hip/hip_bf16.h>

#define NB 2
#define NL 2048
#define ND 2048
#define NH 16
#define NDK 128
// SCALE * log2(e): softmax tracked in exp2 domain
#define SCALE2 0.12753102866606474f

#define AS1 __attribute__((address_space(1)))
#define AS3 __attribute__((address_space(3)))

typedef __attribute__((ext_vector_type(8))) __bf16 bf16x8;
typedef __attribute__((ext_vector_type(4))) float f32x4;

__device__ __forceinline__ unsigned short f2bf(float f) {
    union { float f; unsigned u; } v; v.f = f;
    return (unsigned short)((v.u + 0x7fffu + ((v.u >> 16) & 1u)) >> 16);
}
__device__ __forceinline__ float bf2f(unsigned short h) {
    union { unsigned u; float f; } v; v.u = ((unsigned)h) << 16;
    return v.f;
}

// ============ merged prep: x->bf16 convert + w_qkv transpose + w_o transpose ============
// blockIdx ranges: [0,4096) convert | [4096,7168) w_qkv 64x64 transpose | [7168,8192) w_o.
// Saves 2 kernel launches (~3 us each measured from dispatch-gap accounting, round 6).
__device__ __forceinline__ void transpose_tile(const float* __restrict__ in,
                                               unsigned short* __restrict__ outp,
                                               int R, int C, int bx, int by, int tid)
{
    __shared__ float T[64][65];
    const int tr0 = by * 64;
    const int tc0 = bx * 64;
    const int r = tid >> 2;
    const int q = tid & 3;
    const float* src = in + (size_t)(tr0 + r) * C + tc0 + q * 16;
    #pragma unroll
    for (int i = 0; i < 4; i++) {
        float4 f = *(const float4*)(src + 4 * i);
        T[r][q * 16 + 4 * i + 0] = f.x;
        T[r][q * 16 + 4 * i + 1] = f.y;
        T[r][q * 16 + 4 * i + 2] = f.z;
        T[r][q * 16 + 4 * i + 3] = f.w;
    }
    __syncthreads();
    unsigned short tmp[16];
    #pragma unroll
    for (int i = 0; i < 16; i++) tmp[i] = f2bf(T[q * 16 + i][r]);
    unsigned short* dst = outp + (size_t)(tc0 + r) * R + tr0 + q * 16;
    *(uint4*)dst       = *(uint4*)&tmp[0];
    *(uint4*)(dst + 8) = *(uint4*)&tmp[8];
}

__global__ __launch_bounds__(256)
void prep_kernel(const float* __restrict__ x, unsigned short* __restrict__ x_bf,
                 const float* __restrict__ w_qkv, unsigned short* __restrict__ Wt,
                 const float* __restrict__ w_o, unsigned short* __restrict__ Wt_o)
{
    const int bid = blockIdx.x;
    const int tid = threadIdx.x;
    if (bid < 4096) {
        int i = bid * 256 + tid;
        const float4 a = ((const float4*)x)[2 * i];
        const float4 b = ((const float4*)x)[2 * i + 1];
        unsigned short t[8] = { f2bf(a.x), f2bf(a.y), f2bf(a.z), f2bf(a.w),
                                f2bf(b.x), f2bf(b.y), f2bf(b.z), f2bf(b.w) };
        ((uint4*)x_bf)[i] = *(uint4*)t;
    } else if (bid < 7168) {
        int b2 = bid - 4096;                      // (96, 32): x = b2 % 96, y = b2 / 96
        transpose_tile(w_qkv, Wt, ND, 3 * ND, b2 % 96, b2 / 96, tid);
    } else {
        int b3 = bid - 7168;                      // (32, 32)
        transpose_tile(w_o, Wt_o, ND, ND, b3 & 31, b3 >> 5, tid);
    }
}

// ============ pipelined bf16 GEMM (validated round 10 / round 0): C = A @ Bt^T ==========
// Two barriers per K-step, 3-buffer, vmcnt(8/4/0). DO NOT touch the K-loop schedule:
// rounds 1/2 (4-phase) and 6 (single-barrier) both regressed it (m131-m140 class null).
template<int EPI>
__global__ __launch_bounds__(256)
void gemm_bf16(const unsigned short* __restrict__ A, const unsigned short* __restrict__ Bt,
               float* __restrict__ y_dst,
               unsigned short* __restrict__ q_raw,
               float* __restrict__ k_dst, float* __restrict__ v_dst,
               int K, int NT)
{
    __shared__ __align__(16) unsigned short As[3][128][32];
    __shared__ __align__(16) unsigned short Bs[3][128][32];

    const int tid = threadIdx.x;
    const int lane = tid & 63;
    const int l16 = lane & 15, g = lane >> 4;
    const int w = tid >> 6;
    const int wr = w >> 1, wc = w & 1;

    const int cpn = NT >> 3;
    const int bid = blockIdx.x;
    const int xcd = bid & 7, local = bid >> 3;
    const int bx = xcd * cpn + local % cpn;
    const int by = local / cpn;
    const int m0 = by * 128, n0 = bx * 128;

    const int rowl = (w << 4) + (lane >> 2);
    const int swl = (rowl >> 1) & 3;
    const int kofl = ((lane & 3) ^ swl) << 3;
    const unsigned short* gA = A + (size_t)(m0 + rowl) * K + kofl;
    const unsigned short* gB = Bt + (size_t)(n0 + rowl) * K + kofl;
    const int ldsoff = (w << 10) + (lane << 4);

    f32x4 acc[4][4] = {};
    const int NTILES = K >> 5;

    auto STAGE = [&](int t, int buf) {
        const int k0 = t << 5;
        char* baseA = (char*)&As[buf][0][0] + ldsoff;
        char* baseB = (char*)&Bs[buf][0][0] + ldsoff;
        #pragma unroll
        for (int i = 0; i < 2; i++) {
            __builtin_amdgcn_global_load_lds((const AS1 void*)(gA + (size_t)i * 64 * K + k0),
                                             (AS3 void*)(baseA + i * 4096), 16, 0, 0);
            __builtin_amdgcn_global_load_lds((const AS1 void*)(gB + (size_t)i * 64 * K + k0),
                                             (AS3 void*)(baseB + i * 4096), 16, 0, 0);
        }
    };

    const int rsw = (l16 >> 1) & 3;

    STAGE(0, 0); STAGE(1, 1);

    int bufC = 0;
    for (int t = 0; t < NTILES; t++) {
        const int bufS = (bufC == 0) ? 2 : bufC - 1;
        if (t + 2 < NTILES) STAGE(t + 2, bufS);
        if (t + 2 < NTILES)      asm volatile("s_waitcnt vmcnt(8)" ::: "memory");
        else if (t + 1 < NTILES) asm volatile("s_waitcnt vmcnt(4)" ::: "memory");
        else                     asm volatile("s_waitcnt vmcnt(0)" ::: "memory");
        __builtin_amdgcn_s_barrier();
        __builtin_amdgcn_sched_barrier(0);

        const char* pa = (const char*)&As[bufC][0][0];
        const char* pb = (const char*)&Bs[bufC][0][0];
        bf16x8 af[4], bfr[4];
        #pragma unroll
        for (int r = 0; r < 4; r++) {
            int row = wr * 64 + r * 16 + l16;
            af[r] = *(const bf16x8*)(pa + row * 64 + ((g ^ rsw) << 4));
        }
        #pragma unroll
        for (int c = 0; c < 4; c++) {
            int row = wc * 64 + c * 16 + l16;
            bfr[c] = *(const bf16x8*)(pb + row * 64 + ((g ^ rsw) << 4));
        }
        #pragma unroll
        for (int r = 0; r < 4; r++)
            #pragma unroll
            for (int c = 0; c < 4; c++)
                acc[r][c] = __builtin_amdgcn_mfma_f32_16x16x32_bf16(af[r], bfr[c], acc[r][c], 0, 0, 0);

        __builtin_amdgcn_s_barrier();
        __builtin_amdgcn_sched_barrier(0);
        bufC = (bufC == 2) ? 0 : bufC + 1;
    }

    if constexpr (EPI == 0) {
        const int m3 = bx >> 4, h = bx & 15;
        #pragma unroll
        for (int r = 0; r < 4; r++) {
            int mrow = m0 + wr * 64 + r * 16 + g * 4;
            int b = mrow >> 11, l = mrow & 2047;
            size_t rb = ((size_t)(b * NH + h) * NL + l) * NDK;
            #pragma unroll
            for (int c = 0; c < 4; c++) {
                int dk = wc * 64 + c * 16 + l16;
                #pragma unroll
                for (int i = 0; i < 4; i++) {
                    float val = acc[r][c][i];
                    size_t off = rb + (size_t)i * NDK + dk;
                    if (m3 == 0) q_raw[off] = f2bf(val);
                    else if (m3 == 1) k_dst[off] = val;
                    else v_dst[off] = val;
                }
            }
        }
    } else {
        #pragma unroll
        for (int r = 0; r < 4; r++) {
            int mrow = m0 + wr * 64 + r * 16 + g * 4;
            #pragma unroll
            for (int c = 0; c < 4; c++) {
                int ncol = n0 + wc * 64 + c * 16 + l16;
                #pragma unroll
                for (int i = 0; i < 4; i++)
                    y_dst[(size_t)(mrow + i) * ND + ncol] = acc[r][c][i];
            }
        }
    }
}

// ============ merged mid: RoPE-k (float4) + per-head V transpose ========================
// blockIdx [0,4096): rope | [4096,6144): transpose_v. Independent data; saves 1 launch.
__global__ __launch_bounds__(256)
void mid_kernel(float* __restrict__ kp, unsigned short* __restrict__ k_bf,
                const float* __restrict__ ct, const float* __restrict__ st,
                const float* __restrict__ v, unsigned short* __restrict__ vt)
{
    const int bid = blockIdx.x;
    const int tid = threadIdx.x;
    if (bid < 4096) {
        int idx = bid * 256 + tid;
        int d = (idx & 15) << 2;
        int rr = idx >> 4;
        size_t ro = (size_t)rr * NDK;
        int l = rr & (NL - 1);
        float4 c  = *(const float4*)(ct + l * 64 + d);
        float4 s  = *(const float4*)(st + l * 64 + d);
        float4 t1 = *(const float4*)(kp + ro + d);
        float4 t2 = *(const float4*)(kp + ro + d + 64);
        float4 o1, o2;
        o1.x = t1.x * c.x - t2.x * s.x;  o2.x = t1.x * s.x + t2.x * c.x;
        o1.y = t1.y * c.y - t2.y * s.y;  o2.y = t1.y * s.y + t2.y * c.y;
        o1.z = t1.z * c.z - t2.z * s.z;  o2.z = t1.z * s.z + t2.z * c.z;
        o1.w = t1.w * c.w - t2.w * s.w;  o2.w = t1.w * s.w + t2.w * c.w;
        *(float4*)(kp + ro + d)      = o1;
        *(float4*)(kp + ro + d + 64) = o2;
        unsigned short u1[4] = { f2bf(o1.x), f2bf(o1.y), f2bf(o1.z), f2bf(o1.w) };
        unsigned short u2[4] = { f2bf(o2.x), f2bf(o2.y), f2bf(o2.z), f2bf(o2.w) };
        *(uint2*)(k_bf + ro + d)      = *(uint2*)u1;
        *(uint2*)(k_bf + ro + d + 64) = *(uint2*)u2;
    } else {
        __shared__ float T[64][65];
        int b2 = bid - 4096;                  // (2, 32, 32): x = b2&1, y = (b2>>1)&31, z = b2>>6
        const int bh = b2 >> 6;
        const int l0 = ((b2 >> 1) & 31) * 64;
        const int d0 = (b2 & 1) * 64;
        const int r = tid >> 2;
        const int q = tid & 3;
        const float* src = v + (size_t)bh * NL * NDK + (size_t)(l0 + r) * NDK + d0 + q * 16;
        #pragma unroll
        for (int i = 0; i < 4; i++) {
            float4 f = *(const float4*)(src + 4 * i);
            T[r][q * 16 + 4 * i + 0] = f.x;
            T[r][q * 16 + 4 * i + 1] = f.y;
            T[r][q * 16 + 4 * i + 2] = f.z;
            T[r][q * 16 + 4 * i + 3] = f.w;
        }
        __syncthreads();
        unsigned short tmp[16];
        #pragma unroll
        for (int i = 0; i < 16; i++) tmp[i] = f2bf(T[q * 16 + i][r]);
        unsigned short* dst = vt + (size_t)bh * NDK * NL + (size_t)(d0 + r) * NL + l0 + q * 16;
        *(uint4*)dst       = *(uint4*)&tmp[0];
        *(uint4*)(dst + 8) = *(uint4*)&tmp[8];
    }
}

// ============ MFMA flash attention (round-0 validated: paired two-half blocks) ==========
// grid (32 bh, 16 by); block does jq = 31-by then by -> perfect balance (33 units/block)
// + L2-warm K/V reuse between halves. exp2-domain softmax (arithmetically identical).
__global__ __launch_bounds__(256)
void attn_kernel(const unsigned short* __restrict__ q,
                 const unsigned short* __restrict__ k,
                 const unsigned short* __restrict__ vt,
                 unsigned short* __restrict__ attn_out,
                 const float* __restrict__ ct, const float* __restrict__ st)
{
    __shared__ __align__(16) unsigned short Ks[64][128];
    __shared__ __align__(16) unsigned short Vts[128][64];
    __shared__ __align__(16) unsigned short Ps[4][16][64];

    char* const ksb = (char*)&Ks[0][0];
    char* const vsb = (char*)&Vts[0][0];
    char* const psb = (char*)&Ps[0][0][0];

    const int tid = threadIdx.x, lane = tid & 63, w = tid >> 6;
    const int l16 = lane & 15, g = lane >> 4;
    const int bh = blockIdx.x;
    const int b = bh >> 4, h = bh & 15;
    const size_t base = (size_t)bh * NL * NDK;

    const int krow = tid >> 2;
    const int kq = tid & 3;
    const int kwb = krow * 256 + kq * 64;
    const int kwx = (krow & 7) << 4;
    const int vrow = tid >> 1;
    const int vh = tid & 1;
    const int vwb = vrow * 128 + vh * 64;
    const int vwx = (vrow & 7) << 4;

    const int rdx = (l16 & 7) << 4;

    const unsigned short* const kbase = k + base + (size_t)krow * NDK + kq * 32;
    const unsigned short* const vbase = vt + base + (size_t)vrow * NL + vh * 32;

    for (int half = 0; half < 2; half++) {
        const int jq = half ? (int)blockIdx.y : 31 - (int)blockIdx.y;
        const int qb = jq * 64;

        // ---- Q load with fused RoPE ----
        bf16x8 aq[4];
        {
            const int l = qb + w * 16 + l16;
            const unsigned short* src = q + base + (size_t)l * NDK + g * 8;
            union { bf16x8 v; unsigned short s[8]; } raw[4], outv[4];
            #pragma unroll
            for (int ks2 = 0; ks2 < 4; ks2++) raw[ks2].v = *(const bf16x8*)(src + ks2 * 32);
            const float* cb = ct + (size_t)l * 64 + g * 8;
            const float* sb = st + (size_t)l * 64 + g * 8;
            float cv[2][8], sv2[2][8];
            #pragma unroll
            for (int hh = 0; hh < 2; hh++) {
                float4 c0 = *(const float4*)(cb + 32 * hh);
                float4 c1 = *(const float4*)(cb + 32 * hh + 4);
                float4 s0 = *(const float4*)(sb + 32 * hh);
                float4 s1 = *(const float4*)(sb + 32 * hh + 4);
                cv[hh][0]=c0.x; cv[hh][1]=c0.y; cv[hh][2]=c0.z; cv[hh][3]=c0.w;
                cv[hh][4]=c1.x; cv[hh][5]=c1.y; cv[hh][6]=c1.z; cv[hh][7]=c1.w;
                sv2[hh][0]=s0.x; sv2[hh][1]=s0.y; sv2[hh][2]=s0.z; sv2[hh][3]=s0.w;
                sv2[hh][4]=s1.x; sv2[hh][5]=s1.y; sv2[hh][6]=s1.z; sv2[hh][7]=s1.w;
            }
            #pragma unroll
            for (int hh = 0; hh < 2; hh++)
                #pragma unroll
                for (int j = 0; j < 8; j++) {
                    float t1 = bf2f(raw[hh].s[j]), t2 = bf2f(raw[hh + 2].s[j]);
                    float c = cv[hh][j], s = sv2[hh][j];
                    outv[hh].s[j]     = f2bf(t1 * c - t2 * s);
                    outv[hh + 2].s[j] = f2bf(t1 * s + t2 * c);
                }
            #pragma unroll
            for (int ks2 = 0; ks2 < 4; ks2++) aq[ks2] = outv[ks2].v;
        }

        f32x4 o[8] = {};
        float m_r[4], lv[4];
        #pragma unroll
        for (int i = 0; i < 4; i++) { m_r[i] = -1e30f; lv[i] = 0.f; }

        // ---- T14 prologue: tile 0 into named registers ----
        uint4 pk0, pk1, pk2, pk3, pv0, pv1, pv2, pv3;
        {
            const unsigned short* ks = kbase;           // kv0 = 0
            pk0 = *(const uint4*)(ks);
            pk1 = *(const uint4*)(ks + 8);
            pk2 = *(const uint4*)(ks + 16);
            pk3 = *(const uint4*)(ks + 24);
            const unsigned short* vs = vbase;
            pv0 = *(const uint4*)(vs);
            pv1 = *(const uint4*)(vs + 8);
            pv2 = *(const uint4*)(vs + 16);
            pv3 = *(const uint4*)(vs + 24);
        }

        for (int kv0 = 0; kv0 <= qb; kv0 += 64) {
            __syncthreads();                    // prior reads done; vmcnt(0) lands prefetch
            *(uint4*)(ksb + ((kwb     ) ^ kwx)) = pk0;
            *(uint4*)(ksb + ((kwb + 16) ^ kwx)) = pk1;
            *(uint4*)(ksb + ((kwb + 32) ^ kwx)) = pk2;
            *(uint4*)(ksb + ((kwb + 48) ^ kwx)) = pk3;
            *(uint4*)(vsb + ((vwb     ) ^ vwx)) = pv0;
            *(uint4*)(vsb + ((vwb + 16) ^ vwx)) = pv1;
            *(uint4*)(vsb + ((vwb + 32) ^ vwx)) = pv2;
            *(uint4*)(vsb + ((vwb + 48) ^ vwx)) = pv3;
            __syncthreads();                    // LDS tile visible to all waves

            if (kv0 + 64 <= qb) {               // T14: issue next tile now (inline, named)
                const unsigned short* ks = kbase + (size_t)(kv0 + 64) * NDK;
                pk0 = *(const uint4*)(ks);
                pk1 = *(const uint4*)(ks + 8);
                pk2 = *(const uint4*)(ks + 16);
                pk3 = *(const uint4*)(ks + 24);
                const unsigned short* vs = vbase + kv0 + 64;
                pv0 = *(const uint4*)(vs);
                pv1 = *(const uint4*)(vs + 8);
                pv2 = *(const uint4*)(vs + 16);
                pv3 = *(const uint4*)(vs + 24);
                __builtin_amdgcn_sched_barrier(0);  // pin issue point before compute
            }

            // ---- QK^T: 16 MFMAs ----
            f32x4 sv[4];
            __builtin_amdgcn_s_setprio(1);
            #pragma unroll
            for (int cf = 0; cf < 4; cf++) {
                const int krb = (cf * 16 + l16) * 256 + g * 16;
                f32x4 a = {};
                #pragma unroll
                for (int ks2 = 0; ks2 < 4; ks2++) {
                    bf16x8 kf = *(const bf16x8*)(ksb + ((krb + 64 * ks2) ^ rdx));
                    a = __builtin_amdgcn_mfma_f32_16x16x32_bf16(aq[ks2], kf, a, 0, 0, 0);
                }
                sv[cf] = a;
            }
            __builtin_amdgcn_s_setprio(0);

            // ---- online softmax (exp2 domain, deferred l-sum) ----
            const int kvl = kv0 + l16;
            const int rowb = qb + w * 16 + g * 4;
            #pragma unroll
            for (int i = 0; i < 4; i++) {
                int row = rowb + i;
                float s0 = sv[0][i] * SCALE2;
                float s1 = sv[1][i] * SCALE2;
                float s2 = sv[2][i] * SCALE2;
                float s3 = sv[3][i] * SCALE2;
                if (kvl      > row) s0 = -1e30f;
                if (kvl + 16 > row) s1 = -1e30f;
                if (kvl + 32 > row) s2 = -1e30f;
                if (kvl + 48 > row) s3 = -1e30f;
                float mx = fmaxf(fmaxf(s0, s1), fmaxf(s2, s3));
                mx = fmaxf(mx, __shfl_xor(mx, 1));
                mx = fmaxf(mx, __shfl_xor(mx, 2));
                mx = fmaxf(mx, __shfl_xor(mx, 4));
                mx = fmaxf(mx, __shfl_xor(mx, 8));
                float mnew = fmaxf(m_r[i], mx);
                float fac = exp2f(m_r[i] - mnew);
                float p0 = exp2f(s0 - mnew);
                float p1 = exp2f(s1 - mnew);
                float p2 = exp2f(s2 - mnew);
                float p3 = exp2f(s3 - mnew);
                lv[i] = lv[i] * fac + ((p0 + p1) + (p2 + p3));
                m_r[i] = mnew;
                #pragma unroll
                for (int c8 = 0; c8 < 8; c8++) o[c8][i] *= fac;
                const int pr = g * 4 + i;
                char* pw = psb + w * 2048 + pr * 128;
                const int px = (pr & 7) << 4;
                const int cb2 = l16 << 1;
                *(unsigned short*)(pw + ((cb2)      ^ px)) = f2bf(p0);
                *(unsigned short*)(pw + ((cb2 + 32) ^ px)) = f2bf(p1);
                *(unsigned short*)(pw + ((cb2 + 64) ^ px)) = f2bf(p2);
                *(unsigned short*)(pw + ((cb2 + 96) ^ px)) = f2bf(p3);
            }
            // wave-local LDS RAW (Ps write -> cross-lane read): drain + pin (rule #18)
            asm volatile("s_waitcnt lgkmcnt(0)" ::: "memory");
            __builtin_amdgcn_sched_barrier(0);

            // ---- PV: 16 MFMAs ----
            bf16x8 pf[2];
            #pragma unroll
            for (int kc = 0; kc < 2; kc++)
                pf[kc] = *(const bf16x8*)(psb + w * 2048 + l16 * 128 + ((kc * 64 + g * 16) ^ rdx));
            __builtin_amdgcn_s_setprio(1);
            #pragma unroll
            for (int c8 = 0; c8 < 8; c8++) {
                const int vrb = (c8 * 16 + l16) * 128 + g * 16;
                #pragma unroll
                for (int kc = 0; kc < 2; kc++) {
                    bf16x8 vf = *(const bf16x8*)(vsb + ((vrb + kc * 64) ^ rdx));
                    o[c8] = __builtin_amdgcn_mfma_f32_16x16x32_bf16(pf[kc], vf, o[c8], 0, 0, 0);
                }
            }
            __builtin_amdgcn_s_setprio(0);
        }

        #pragma unroll
        for (int i = 0; i < 4; i++) {
            float ls = lv[i];
            ls += __shfl_xor(ls, 1);
            ls += __shfl_xor(ls, 2);
            ls += __shfl_xor(ls, 4);
            ls += __shfl_xor(ls, 8);
            float inv = 1.0f / ls;
            int qrow = qb + w * 16 + g * 4 + i;
            size_t rb = ((size_t)(b * NL + qrow)) * ND + h * NDK;
            #pragma unroll
            for (int c8 = 0; c8 < 8; c8++)
                attn_out[rb + c8 * 16 + l16] = f2bf(o[c8][i] * inv);
        }
    }
}

__global__ void ws_signature_kernel(float* y) { if (threadIdx.x == 0) y[0] = 12345.0f; }

extern "C" void kernel_launch(void* const* d_in, const int* in_sizes, int n_in,
                              void* d_out, int out_size, void* d_ws, size_t ws_size,
                              hipStream_t stream)
{
    const float* x     = (const float*)d_in[0];
    const float* w_qkv = (const float*)d_in[1];
    const float* w_o   = (const float*)d_in[2];
    const float* ct    = (const float*)d_in[3];
    const float* st    = (const float*)d_in[4];

    const size_t NTOK = (size_t)NB * NL * ND;
    float* y_out = (float*)d_out;
    float* k_out = y_out + NTOK;
    float* v_out = y_out + 2 * NTOK;

    const size_t need = (6 * NTOK + 4 * (size_t)ND * ND) * sizeof(unsigned short);
    if (ws_size < need) {
        ws_signature_kernel<<<1, 64, 0, stream>>>(y_out);
        return;
    }
    unsigned short* x_bf  = (unsigned short*)d_ws;
    unsigned short* Wt    = x_bf + NTOK;
    unsigned short* Wt_o  = Wt + (size_t)3 * ND * ND;
    unsigned short* q_raw = Wt_o + (size_t)ND * ND;
    unsigned short* q_bf  = q_raw + NTOK;        // unused (kept for layout)
    unsigned short* k_bf  = q_bf + NTOK;
    unsigned short* Vt    = k_bf + NTOK;
    unsigned short* a_bf  = Vt + NTOK;

    prep_kernel<<<8192, 256, 0, stream>>>(x, x_bf, w_qkv, Wt, w_o, Wt_o);
    gemm_bf16<0><<<1536, 256, 0, stream>>>(x_bf, Wt, nullptr, q_raw, k_out, v_out, ND, 48);
    mid_kernel<<<6144, 256, 0, stream>>>(k_out, k_bf, ct, st, v_out, Vt);
    attn_kernel<<<dim3(32, 16), 256, 0, stream>>>(q_raw, k_bf, Vt, a_bf, ct, st);
    gemm_bf16<1><<<512, 256, 0, stream>>>(a_bf, Wt_o, y_out, nullptr, nullptr, nullptr, ND, 16);
}